// Round 8
// baseline (216.919 us; speedup 1.0000x reference)
//
#include <hip/hip_runtime.h>
#include <hip/hip_bf16.h>

typedef __bf16 bf16_t;
typedef bf16_t bf16x8 __attribute__((ext_vector_type(8)));
typedef float f32x4 __attribute__((ext_vector_type(4)));
typedef float f32x16 __attribute__((ext_vector_type(16)));

static __device__ __forceinline__ f32x4 mfma16(bf16x8 a, bf16x8 b, f32x4 c) {
  return __builtin_amdgcn_mfma_f32_16x16x32_bf16(a, b, c, 0, 0, 0);
}
static __device__ __forceinline__ f32x16 mfma32(bf16x8 a, bf16x8 b, f32x16 c) {
  return __builtin_amdgcn_mfma_f32_32x32x16_bf16(a, b, c, 0, 0, 0);
}

static __device__ __forceinline__ void gload_lds16(const bf16_t* g, bf16_t* l) {
  __builtin_amdgcn_global_load_lds(
      (const __attribute__((address_space(1))) void*)g,
      (__attribute__((address_space(3))) void*)l, 16, 0, 0);
}

static __device__ __forceinline__ unsigned pkbf(float a, float b) {
  union { bf16_t h[2]; unsigned u; } p;
  p.h[0] = (bf16_t)a; p.h[1] = (bf16_t)b;
  return p.u;
}
static __device__ __forceinline__ void pl32swap(unsigned& a, unsigned& b) {
  asm volatile("v_permlane32_swap_b32 %0, %1" : "+v"(a), "+v"(b));
}

// ---------------------------------------------------------------- tiny kernels

__global__ __launch_bounds__(64) void lam_kernel(const float* __restrict__ lq1,
                                                 const float* __restrict__ lk1,
                                                 const float* __restrict__ lq2,
                                                 const float* __restrict__ lk2,
                                                 float* __restrict__ lamp) {
  int l = threadIdx.x;
  float a = lq1[l] * lk1[l];
  float b = lq2[l] * lk2[l];
  #pragma unroll
  for (int msk = 32; msk; msk >>= 1) {
    a += __shfl_xor(a, msk);
    b += __shfl_xor(b, msk);
  }
  if (l == 0) lamp[0] = __expf(a) - __expf(b) + 0.8f;
}

__global__ __launch_bounds__(256) void cvt_x_kernel(const float* __restrict__ x,
                                                    bf16_t* __restrict__ xb) {
  int i = (blockIdx.x * 256 + threadIdx.x) * 4;
  float4 v = *reinterpret_cast<const float4*>(x + i);
  union { bf16_t h[4]; uint2 u; } pk;
  pk.h[0] = (bf16_t)v.x; pk.h[1] = (bf16_t)v.y;
  pk.h[2] = (bf16_t)v.z; pk.h[3] = (bf16_t)v.w;
  *reinterpret_cast<uint2*>(xb + i) = pk.u;
}

// W: [K][N] fp32 row-major  ->  Wt: [N][K] bf16 row-major
__global__ __launch_bounds__(256) void transpose_cvt(const float* __restrict__ W,
                                                     bf16_t* __restrict__ Wt,
                                                     int K, int N) {
  __shared__ float tile[32][33];
  int n0 = blockIdx.x * 32, k0 = blockIdx.y * 32;
  int x = threadIdx.x, y = threadIdx.y;  // 32 x 8
  #pragma unroll
  for (int i = 0; i < 32; i += 8)
    tile[y + i][x] = W[(size_t)(k0 + y + i) * N + n0 + x];
  __syncthreads();
  #pragma unroll
  for (int i = 0; i < 32; i += 8)
    Wt[(size_t)(n0 + y + i) * K + k0 + x] = (bf16_t)tile[x][y + i];
}

// Ob = 0.2*(Ob1 - lam*Ob2), bf16x8 vectorized
__global__ __launch_bounds__(256) void combine_kernel(const bf16_t* __restrict__ Ob1,
                                                      const bf16_t* __restrict__ Ob2,
                                                      bf16_t* __restrict__ Ob,
                                                      const float* __restrict__ lamp) {
  int i = (blockIdx.x * 256 + threadIdx.x) * 8;
  const float lam = lamp[0];
  bf16x8 a = *reinterpret_cast<const bf16x8*>(Ob1 + i);
  bf16x8 c = *reinterpret_cast<const bf16x8*>(Ob2 + i);
  bf16x8 r;
  #pragma unroll
  for (int j = 0; j < 8; ++j)
    r[j] = (bf16_t)(0.2f * ((float)a[j] - lam * (float)c[j]));
  *reinterpret_cast<bf16x8*>(Ob + i) = r;
}

// ---------------------------------------------------------------- GEMM (A[M][K] x Bt[N][K]^T)

template <typename OutT>
static __device__ __forceinline__ void gemm_bt_body(const bf16_t* __restrict__ A,
                                                    const bf16_t* __restrict__ Bt,
                                                    OutT* __restrict__ C,
                                                    int M, int N, int K,
                                                    bool vtrans) {
  __shared__ bf16_t As[128 * 32];
  __shared__ bf16_t Bs[128 * 32];
  const int tid = threadIdx.x;
  const int w = tid >> 6, lane = tid & 63;
  const int g = lane >> 4, l15 = lane & 15;
  const int wm = w >> 1, wn = w & 1;

  // T1: XCD-contiguous block swizzle (n = gridDim.x*gridDim.y divisible by 8)
  const int nbx = gridDim.x;
  const int idx = blockIdx.y * nbx + blockIdx.x;
  const int qq = (nbx * gridDim.y) >> 3;
  const int sidx = (idx & 7) * qq + (idx >> 3);
  const int rowBase = (sidx / nbx) * 128, colBase = (sidx % nbx) * 128;

  const int c0 = 2 * w, c1 = 2 * w + 1;
  const int srow0 = 16 * c0 + (lane >> 2);
  const int srow1 = 16 * c1 + (lane >> 2);
  const int scol = (lane & 3) * 8;

  f32x4 acc[4][4] = {};

  for (int k0 = 0; k0 < K; k0 += 32) {
    __syncthreads();
    gload_lds16(A + (size_t)(rowBase + srow0) * K + k0 + scol, &As[c0 * 512]);
    gload_lds16(A + (size_t)(rowBase + srow1) * K + k0 + scol, &As[c1 * 512]);
    gload_lds16(Bt + (size_t)(colBase + srow0) * K + k0 + scol, &Bs[c0 * 512]);
    gload_lds16(Bt + (size_t)(colBase + srow1) * K + k0 + scol, &Bs[c1 * 512]);
    __syncthreads();

    bf16x8 bfr[4];
    #pragma unroll
    for (int j = 0; j < 4; ++j)
      bfr[j] = *reinterpret_cast<const bf16x8*>(&Bs[(wn * 64 + j * 16 + l15) * 32 + g * 8]);
    #pragma unroll
    for (int i = 0; i < 4; ++i) {
      bf16x8 afr = *reinterpret_cast<const bf16x8*>(&As[(wm * 64 + i * 16 + l15) * 32 + g * 8]);
      #pragma unroll
      for (int j = 0; j < 4; ++j)
        acc[i][j] = mfma16(afr, bfr[j], acc[i][j]);
    }
  }

  if (vtrans) {
    #pragma unroll
    for (int i = 0; i < 4; ++i) {
      #pragma unroll
      for (int j = 0; j < 4; ++j) {
        int row = rowBase + wm * 64 + i * 16 + 4 * g;  // global s in [0,4096)
        int col = colBase + wn * 64 + j * 16 + l15;    // [0,2048)
        int bb = row >> 11, s = row & 2047;
        union { bf16_t h[4]; uint2 u; } pk;
        #pragma unroll
        for (int r = 0; r < 4; ++r) pk.h[r] = (bf16_t)acc[i][j][r];
        *reinterpret_cast<uint2*>(
            (bf16_t*)C + ((size_t)bb * 2048 + col) * 2048 + s) = pk.u;
      }
    }
  } else {
    #pragma unroll
    for (int i = 0; i < 4; ++i) {
      #pragma unroll
      for (int j = 0; j < 4; ++j) {
        int row = rowBase + wm * 64 + i * 16 + 4 * g;
        int col = colBase + wn * 64 + j * 16 + l15;
        #pragma unroll
        for (int r = 0; r < 4; ++r)
          C[(size_t)(row + r) * N + col] = (OutT)acc[i][j][r];
      }
    }
  }
}

__global__ __launch_bounds__(256) void gemm_qkv(const bf16_t* __restrict__ xb,
                                                const bf16_t* __restrict__ Wqt,
                                                const bf16_t* __restrict__ Wkt,
                                                const bf16_t* __restrict__ Wvt,
                                                bf16_t* __restrict__ Q,
                                                bf16_t* __restrict__ K,
                                                bf16_t* __restrict__ Vtg) {
  const bf16_t* Bt = (blockIdx.z == 0) ? Wqt : (blockIdx.z == 1) ? Wkt : Wvt;
  bf16_t* C = (blockIdx.z == 0) ? Q : (blockIdx.z == 1) ? K : Vtg;
  gemm_bt_body<bf16_t>(xb, Bt, C, 4096, 2048, 1024, blockIdx.z == 2);
}

__global__ __launch_bounds__(256) void gemm_out(const bf16_t* __restrict__ Ob,
                                                const bf16_t* __restrict__ Wot,
                                                float* __restrict__ out) {
  gemm_bt_body<float>(Ob, Wot, out, 4096, 1024, 1024, false);
}

// ---------------------------------------------------------------- attention
// 1024 uniform blocks x 256 thr (4 waves), 4 blocks/CU (32.25KB LDS, ~100 VGPR)
// -> 16 waves/CU, 4 independent barrier groups. Block = (pair p, bh, rhalf,
// comp): ONE component, 64 q-rows (rhalf half of the 128-row tile), tile pair
// {p, 15-p} sequential, KVBLK=128 -> exactly 17 iterations for EVERY block
// (dispatch-order independent balance). Waves: rowg = w&1 (32 rows),
// keyh = w>>1 (64-key half). Key-half partials combine by addition (no-max
// softmax) via freed LDS; per-comp normalized output -> Ob1/Ob2; the
// cross-comp o1/l1 - lam*o2/l2 combine is the elementwise combine_kernel.
// LDS (32KB): K [key][128B swz] | V at +16KB [d][256B swz]. Compute/staging
// code = round-7 verified lineage with the comp loop deleted.

__global__ __launch_bounds__(256, 1)
void attn_kernel(const bf16_t* __restrict__ Qg, const bf16_t* __restrict__ Kg,
                 const bf16_t* __restrict__ Vtg, bf16_t* __restrict__ Ob1,
                 bf16_t* __restrict__ Ob2) {
  __shared__ __align__(16) char ldsbuf[32768];
  __shared__ float lsArr[2][32];

  const int tid = threadIdx.x;
  const int w = tid >> 6, lane = tid & 63;
  const int l31 = lane & 31, hi = lane >> 5;
  const int sw7 = l31 & 7;
  const int rowg = w & 1, keyh = w >> 1;
  const int bx = blockIdx.x;
  const int comp = bx & 1;
  const int rhalf = (bx >> 1) & 1;
  const int bh = (bx >> 2) & 31;
  const int p = bx >> 7;            // pair 0..7 -> tiles {p, 15-p}
  const int b = bh >> 4, h = bh & 15;
  const int rowB = b * 2048;
  const float cexp = 0.125f * 1.44269504088896340736f;  // scale * log2(e)
  bf16_t* __restrict__ Obc = comp ? Ob2 : Ob1;

  // ---- staging constants (round-3/4/7 lineage, comp fixed per block)
  const int lk8 = lane >> 3;               // K: row-within-8
  const int sc8 = (lane & 7) ^ lk8;        // K: pre-swizzled source chunk
  const int lk4 = lane >> 4;               // V: row-within-4
  const int wv = (w - 2) & 1;
  const size_t kOff = (size_t)(rowB + ((w & 1) << 6) + lk8) * 2048 +
                      comp * 1024 + h * 64 + sc8 * 8;               // w<2
  const size_t vOff = ((size_t)b * 2048 + comp * 1024 + h * 64 +
                       (wv << 5) + lk4) * 2048;                     // w>=2

  auto stage = [&](char* bufb, int j0) {
    if (w < 2) {
      const bf16_t* src = Kg + kOff + (size_t)j0 * 2048;
      char* dst = bufb + w * 8192;
      #pragma unroll
      for (int t = 0; t < 8; ++t)
        gload_lds16(src + (size_t)t * (8 * 2048), (bf16_t*)(dst + t * 1024));
    } else {
      const bf16_t* src = Vtg + vOff + j0;
      char* dst = bufb + 16384 + wv * 8192;
      #pragma unroll
      for (int t = 0; t < 8; ++t) {
        int sc16 = (lane & 15) ^ (((t & 1) << 2) + lk4);
        gload_lds16(src + (size_t)t * (4 * 2048) + sc16 * 8,
                    (bf16_t*)(dst + t * 1024));
      }
    }
  };

  f32x16 o[2];   // [d-half], one comp
  float ls;
  bf16x8 qf[4];

  // ---- phase-end: combine key-half partials (waves 2,3 donate; 0,1 read),
  // normalize by 1/rowsum, store this comp's half to Obc.
  auto finalize = [&](int q0, char* scratch) {
    float* sf = (float*)scratch;
    #pragma unroll
    for (int db = 0; db < 2; ++db) {
      __syncthreads();
      if (w >= 2) {
        float* bp = sf + (size_t)((w - 2) * 64 + lane) * 17;
        #pragma unroll
        for (int e = 0; e < 16; ++e) bp[e] = o[db][e];
        if (db == 0) bp[16] = ls;
      }
      __syncthreads();
      if (w < 2) {
        const float* bp = sf + (size_t)(w * 64 + lane) * 17;
        #pragma unroll
        for (int e = 0; e < 16; ++e) o[db][e] += bp[e];
        if (db == 0) ls += bp[16];
      }
    }
    __syncthreads();  // scratch reads done
    if (w < 2) {
      float tot = ls + __shfl_xor(ls, 32);
      lsArr[w][l31] = 1.f / tot;
    }
    __syncthreads();
    if (w < 2) {
      #pragma unroll
      for (int e = 0; e < 16; ++e) {
        int ql = (e & 3) + 8 * (e >> 2) + 4 * hi;
        float inv = lsArr[w][ql];
        int row = rowB + q0 + rhalf * 64 + w * 32 + ql;
        size_t rb = (size_t)row * 1024 + h * 64 + l31;
        Obc[rb]      = (bf16_t)(o[0][e] * inv);
        Obc[rb + 32] = (bf16_t)(o[1][e] * inv);
      }
    }
  };

  #pragma unroll 1
  for (int i = 0; i <= 16; ++i) {
    const int q0 = (i > p ? 15 - p : p) << 7;
    const int j0 = (i > p ? i - p - 1 : i) << 7;

    __syncthreads();          // everyone done with buffer (compute/finalize)
    stage(ldsbuf, j0);        // async global->LDS

    if (i == 0 || i == p + 1) {  // phase start under staging latency
      #pragma unroll
      for (int s = 0; s < 4; ++s)
        qf[s] = *reinterpret_cast<const bf16x8*>(
            Qg + (size_t)(rowB + q0 + rhalf * 64 + rowg * 32 + l31) * 2048 +
            comp * 1024 + h * 64 + s * 16 + hi * 8);
      o[0] = (f32x16)0.f;
      o[1] = (f32x16)0.f;
      ls = 0.f;
    }

    __syncthreads();          // staged data visible (drains vmcnt)

    const char* bufb = (const char*)ldsbuf;
    const int rowbase = q0 + rhalf * 64 + rowg * 32;
    const int qg = rowbase + l31;
    const bool active = (j0 + keyh * 64) <= (rowbase + 31);
    if (active) {
      const bool maskt = (j0 + keyh * 64 + 63) > rowbase;
      const char* Kb = bufb + keyh * 8192;
      const char* Vb = bufb + 16384;
      // ---- per 32-key half: S' = K Q^T -> P -> pa -> PV
      #pragma unroll
      for (int kb = 0; kb < 2; ++kb) {
        f32x16 sA = {};
        #pragma unroll
        for (int s = 0; s < 4; ++s) {
          int xo = ((2 * s + hi) ^ sw7) << 4;
          bf16x8 kf = *reinterpret_cast<const bf16x8*>(
              Kb + (kb * 32 + l31) * 128 + xo);
          sA = mfma32(kf, qf[s], sA);
        }
        float pv[16];
        #pragma unroll
        for (int e = 0; e < 16; ++e) {
          float v = __builtin_exp2f(sA[e] * cexp);
          if (maskt) {
            int krow = (e & 3) + 8 * (e >> 2) + 4 * hi;
            if (j0 + keyh * 64 + kb * 32 + krow > qg) v = 0.f;
          }
          pv[e] = v;
          ls += v;
        }
        bf16x8 pa[2];
        #pragma unroll
        for (int sp = 0; sp < 2; ++sp) {
          unsigned u0 = pkbf(pv[8 * sp + 0], pv[8 * sp + 1]);
          unsigned u1 = pkbf(pv[8 * sp + 2], pv[8 * sp + 3]);
          unsigned v0 = pkbf(pv[8 * sp + 4], pv[8 * sp + 5]);
          unsigned v1 = pkbf(pv[8 * sp + 6], pv[8 * sp + 7]);
          pl32swap(u0, v0);
          pl32swap(u1, v1);
          union { uint4 u; bf16x8 f; } cvt;
          cvt.u = make_uint4(u0, u1, v0, v1);
          pa[sp] = cvt.f;
        }
        #pragma unroll
        for (int sp = 0; sp < 2; ++sp) {
          int s = kb * 2 + sp;
          int sl = ((keyh * 8) | ((2 * s + hi) ^ sw7)) << 4;
          bf16x8 vf0 = *reinterpret_cast<const bf16x8*>(Vb + l31 * 256 + sl);
          bf16x8 vf1 = *reinterpret_cast<const bf16x8*>(Vb + (32 + l31) * 256 + sl);
          o[0] = mfma32(pa[sp], vf0, o[0]);
          o[1] = mfma32(pa[sp], vf1, o[1]);
        }
      }
    }

    if (i == p || i == 16) finalize(q0, ldsbuf);
  }
}

// ---------------------------------------------------------------- launch

extern "C" void kernel_launch(void* const* d_in, const int* in_sizes, int n_in,
                              void* d_out, int out_size, void* d_ws, size_t ws_size,
                              hipStream_t stream) {
  const float* x   = (const float*)d_in[0];
  const float* Wq  = (const float*)d_in[1];
  const float* Wk  = (const float*)d_in[2];
  const float* Wv  = (const float*)d_in[3];
  const float* Wo  = (const float*)d_in[4];
  const float* lq1 = (const float*)d_in[5];
  const float* lk1 = (const float*)d_in[6];
  const float* lq2 = (const float*)d_in[7];
  const float* lk2 = (const float*)d_in[8];
  float* out = (float*)d_out;

  char* ws = (char*)d_ws;
  size_t off = 0;
  auto alloc = [&](size_t bytes) -> char* {
    char* p = ws + off;
    off += (bytes + 255) & ~(size_t)255;
    return p;
  };
  bf16_t* xb  = (bf16_t*)alloc((size_t)4096 * 1024 * 2);
  bf16_t* Wqt = (bf16_t*)alloc((size_t)2048 * 1024 * 2);
  bf16_t* Wkt = (bf16_t*)alloc((size_t)2048 * 1024 * 2);
  bf16_t* Wvt = (bf16_t*)alloc((size_t)2048 * 1024 * 2);
  bf16_t* Wot = (bf16_t*)alloc((size_t)1024 * 1024 * 2);
  bf16_t* Qb  = (bf16_t*)alloc((size_t)4096 * 2048 * 2);
  bf16_t* Kb  = (bf16_t*)alloc((size_t)4096 * 2048 * 2);
  bf16_t* Vtg = (bf16_t*)alloc((size_t)4096 * 2048 * 2);
  bf16_t* Ob  = (bf16_t*)alloc((size_t)4096 * 1024 * 2);
  float*  lamp = (float*)alloc(256);

  // Attn partial outputs alias workspace that is DEAD once gemm_qkv ran and
  // is fully rewritten at the start of every call (graph-replay safe):
  // Ob1 <- xb (exactly 8MB); Ob2 <- Wqt..Wkt (two contiguous 4MB allocs).
  bf16_t* Ob1 = xb;
  bf16_t* Ob2 = Wqt;

  lam_kernel<<<1, 64, 0, stream>>>(lq1, lk1, lq2, lk2, lamp);
  cvt_x_kernel<<<4096, 256, 0, stream>>>(x, xb);
  transpose_cvt<<<dim3(64, 32), dim3(32, 8), 0, stream>>>(Wq, Wqt, 1024, 2048);
  transpose_cvt<<<dim3(64, 32), dim3(32, 8), 0, stream>>>(Wk, Wkt, 1024, 2048);
  transpose_cvt<<<dim3(64, 32), dim3(32, 8), 0, stream>>>(Wv, Wvt, 1024, 2048);
  transpose_cvt<<<dim3(32, 32), dim3(32, 8), 0, stream>>>(Wo, Wot, 1024, 1024);
  gemm_qkv<<<dim3(16, 32, 3), 256, 0, stream>>>(xb, Wqt, Wkt, Wvt, Qb, Kb, Vtg);
  attn_kernel<<<1024, 256, 0, stream>>>(Qb, Kb, Vtg, Ob1, Ob2);
  combine_kernel<<<2048, 256, 0, stream>>>(Ob1, Ob2, Ob, lamp);
  gemm_out<<<dim3(8, 32), 256, 0, stream>>>(Ob, Wot, out);
}

// Round 9
// 216.531 us; speedup vs baseline: 1.0018x; 1.0018x over previous
//
#include <hip/hip_runtime.h>
#include <hip/hip_bf16.h>

typedef __bf16 bf16_t;
typedef bf16_t bf16x8 __attribute__((ext_vector_type(8)));
typedef float f32x4 __attribute__((ext_vector_type(4)));
typedef float f32x16 __attribute__((ext_vector_type(16)));

static __device__ __forceinline__ f32x4 mfma16(bf16x8 a, bf16x8 b, f32x4 c) {
  return __builtin_amdgcn_mfma_f32_16x16x32_bf16(a, b, c, 0, 0, 0);
}
static __device__ __forceinline__ f32x16 mfma32(bf16x8 a, bf16x8 b, f32x16 c) {
  return __builtin_amdgcn_mfma_f32_32x32x16_bf16(a, b, c, 0, 0, 0);
}

static __device__ __forceinline__ void gload_lds16(const bf16_t* g, bf16_t* l) {
  __builtin_amdgcn_global_load_lds(
      (const __attribute__((address_space(1))) void*)g,
      (__attribute__((address_space(3))) void*)l, 16, 0, 0);
}

static __device__ __forceinline__ unsigned pkbf(float a, float b) {
  union { bf16_t h[2]; unsigned u; } p;
  p.h[0] = (bf16_t)a; p.h[1] = (bf16_t)b;
  return p.u;
}
static __device__ __forceinline__ void pl32swap(unsigned& a, unsigned& b) {
  asm volatile("v_permlane32_swap_b32 %0, %1" : "+v"(a), "+v"(b));
}

// ---------------------------------------------------------------- tiny kernels

__global__ __launch_bounds__(64) void lam_kernel(const float* __restrict__ lq1,
                                                 const float* __restrict__ lk1,
                                                 const float* __restrict__ lq2,
                                                 const float* __restrict__ lk2,
                                                 float* __restrict__ lamp) {
  int l = threadIdx.x;
  float a = lq1[l] * lk1[l];
  float b = lq2[l] * lk2[l];
  #pragma unroll
  for (int msk = 32; msk; msk >>= 1) {
    a += __shfl_xor(a, msk);
    b += __shfl_xor(b, msk);
  }
  if (l == 0) lamp[0] = __expf(a) - __expf(b) + 0.8f;
}

__global__ __launch_bounds__(256) void cvt_x_kernel(const float* __restrict__ x,
                                                    bf16_t* __restrict__ xb) {
  int i = (blockIdx.x * 256 + threadIdx.x) * 4;
  float4 v = *reinterpret_cast<const float4*>(x + i);
  union { bf16_t h[4]; uint2 u; } pk;
  pk.h[0] = (bf16_t)v.x; pk.h[1] = (bf16_t)v.y;
  pk.h[2] = (bf16_t)v.z; pk.h[3] = (bf16_t)v.w;
  *reinterpret_cast<uint2*>(xb + i) = pk.u;
}

// W: [K][N] fp32 row-major  ->  Wt: [N][K] bf16 row-major, scaled
__global__ __launch_bounds__(256) void transpose_cvt(const float* __restrict__ W,
                                                     bf16_t* __restrict__ Wt,
                                                     int K, int N, float scale) {
  __shared__ float tile[32][33];
  int n0 = blockIdx.x * 32, k0 = blockIdx.y * 32;
  int x = threadIdx.x, y = threadIdx.y;  // 32 x 8
  #pragma unroll
  for (int i = 0; i < 32; i += 8)
    tile[y + i][x] = W[(size_t)(k0 + y + i) * N + n0 + x];
  __syncthreads();
  #pragma unroll
  for (int i = 0; i < 32; i += 8)
    Wt[(size_t)(n0 + y + i) * K + k0 + x] = (bf16_t)(tile[x][y + i] * scale);
}

// Ob = 0.2*(Ob1 - lam*Ob2), bf16x8 vectorized
__global__ __launch_bounds__(256) void combine_kernel(const bf16_t* __restrict__ Ob1,
                                                      const bf16_t* __restrict__ Ob2,
                                                      bf16_t* __restrict__ Ob,
                                                      const float* __restrict__ lamp) {
  int i = (blockIdx.x * 256 + threadIdx.x) * 8;
  const float lam = lamp[0];
  bf16x8 a = *reinterpret_cast<const bf16x8*>(Ob1 + i);
  bf16x8 c = *reinterpret_cast<const bf16x8*>(Ob2 + i);
  bf16x8 r;
  #pragma unroll
  for (int j = 0; j < 8; ++j)
    r[j] = (bf16_t)(0.2f * ((float)a[j] - lam * (float)c[j]));
  *reinterpret_cast<bf16x8*>(Ob + i) = r;
}

// ---------------------------------------------------------------- GEMM (A[M][K] x Bt[N][K]^T)

template <typename OutT>
static __device__ __forceinline__ void gemm_bt_body(const bf16_t* __restrict__ A,
                                                    const bf16_t* __restrict__ Bt,
                                                    OutT* __restrict__ C,
                                                    int M, int N, int K,
                                                    bool vtrans) {
  __shared__ bf16_t As[128 * 32];
  __shared__ bf16_t Bs[128 * 32];
  const int tid = threadIdx.x;
  const int w = tid >> 6, lane = tid & 63;
  const int g = lane >> 4, l15 = lane & 15;
  const int wm = w >> 1, wn = w & 1;

  // T1: XCD-contiguous block swizzle (n = gridDim.x*gridDim.y divisible by 8)
  const int nbx = gridDim.x;
  const int idx = blockIdx.y * nbx + blockIdx.x;
  const int qq = (nbx * gridDim.y) >> 3;
  const int sidx = (idx & 7) * qq + (idx >> 3);
  const int rowBase = (sidx / nbx) * 128, colBase = (sidx % nbx) * 128;

  const int c0 = 2 * w, c1 = 2 * w + 1;
  const int srow0 = 16 * c0 + (lane >> 2);
  const int srow1 = 16 * c1 + (lane >> 2);
  const int scol = (lane & 3) * 8;

  f32x4 acc[4][4] = {};

  for (int k0 = 0; k0 < K; k0 += 32) {
    __syncthreads();
    gload_lds16(A + (size_t)(rowBase + srow0) * K + k0 + scol, &As[c0 * 512]);
    gload_lds16(A + (size_t)(rowBase + srow1) * K + k0 + scol, &As[c1 * 512]);
    gload_lds16(Bt + (size_t)(colBase + srow0) * K + k0 + scol, &Bs[c0 * 512]);
    gload_lds16(Bt + (size_t)(colBase + srow1) * K + k0 + scol, &Bs[c1 * 512]);
    __syncthreads();

    bf16x8 bfr[4];
    #pragma unroll
    for (int j = 0; j < 4; ++j)
      bfr[j] = *reinterpret_cast<const bf16x8*>(&Bs[(wn * 64 + j * 16 + l15) * 32 + g * 8]);
    #pragma unroll
    for (int i = 0; i < 4; ++i) {
      bf16x8 afr = *reinterpret_cast<const bf16x8*>(&As[(wm * 64 + i * 16 + l15) * 32 + g * 8]);
      #pragma unroll
      for (int j = 0; j < 4; ++j)
        acc[i][j] = mfma16(afr, bfr[j], acc[i][j]);
    }
  }

  if (vtrans) {
    #pragma unroll
    for (int i = 0; i < 4; ++i) {
      #pragma unroll
      for (int j = 0; j < 4; ++j) {
        int row = rowBase + wm * 64 + i * 16 + 4 * g;  // global s in [0,4096)
        int col = colBase + wn * 64 + j * 16 + l15;    // [0,2048)
        int bb = row >> 11, s = row & 2047;
        union { bf16_t h[4]; uint2 u; } pk;
        #pragma unroll
        for (int r = 0; r < 4; ++r) pk.h[r] = (bf16_t)acc[i][j][r];
        *reinterpret_cast<uint2*>(
            (bf16_t*)C + ((size_t)bb * 2048 + col) * 2048 + s) = pk.u;
      }
    }
  } else {
    #pragma unroll
    for (int i = 0; i < 4; ++i) {
      #pragma unroll
      for (int j = 0; j < 4; ++j) {
        int row = rowBase + wm * 64 + i * 16 + 4 * g;
        int col = colBase + wn * 64 + j * 16 + l15;
        #pragma unroll
        for (int r = 0; r < 4; ++r)
          C[(size_t)(row + r) * N + col] = (OutT)acc[i][j][r];
      }
    }
  }
}

__global__ __launch_bounds__(256) void gemm_qkv(const bf16_t* __restrict__ xb,
                                                const bf16_t* __restrict__ Wqt,
                                                const bf16_t* __restrict__ Wkt,
                                                const bf16_t* __restrict__ Wvt,
                                                bf16_t* __restrict__ Q,
                                                bf16_t* __restrict__ K,
                                                bf16_t* __restrict__ Vtg) {
  const bf16_t* Bt = (blockIdx.z == 0) ? Wqt : (blockIdx.z == 1) ? Wkt : Wvt;
  bf16_t* C = (blockIdx.z == 0) ? Q : (blockIdx.z == 1) ? K : Vtg;
  gemm_bt_body<bf16_t>(xb, Bt, C, 4096, 2048, 1024, blockIdx.z == 2);
}

__global__ __launch_bounds__(256) void gemm_out(const bf16_t* __restrict__ Ob,
                                                const bf16_t* __restrict__ Wot,
                                                float* __restrict__ out) {
  gemm_bt_body<float>(Ob, Wot, out, 4096, 1024, 1024, false);
}

// ---------------------------------------------------------------- attention
// 512 blocks x 512 thr (8 waves), 2 blocks/CU (33.5KB LDS) -> 16 waves/CU,
// two independent barrier groups per CU (breaks R7's 2-wave/SIMD lockstep).
// Block = (pair p, bh, comp): ONE component (comps read DISJOINT K/V data ->
// zero traffic duplication), 128 q-rows, tile pair {p,15-p} sequential,
// KVBLK=128 -> exactly 17 iterations per block. Waves: rowg = w&3 (32 rows),
// keyh = w>>2 (64-key half) — R7's verified layout with the comp loop deleted.
// Q is pre-scaled by 0.125*log2e (folded into Wqt) so exp2 takes sA directly.
// Per-comp normalized output -> Ob1/Ob2; lam combine = combine_kernel.
// LDS (32KB): K [key][128B swz] | V at +16KB [d][256B swz].

__global__ __launch_bounds__(512, 1)
void attn_kernel(const bf16_t* __restrict__ Qg, const bf16_t* __restrict__ Kg,
                 const bf16_t* __restrict__ Vtg, bf16_t* __restrict__ Ob1,
                 bf16_t* __restrict__ Ob2) {
  __shared__ __align__(16) char ldsbuf[32768];
  __shared__ float lsArr[4][32];
  __shared__ float lsDon[4][64];

  const int tid = threadIdx.x;
  const int w = tid >> 6, lane = tid & 63;
  const int l31 = lane & 31, hi = lane >> 5;
  const int sw7 = l31 & 7;
  const int rowg = w & 3, keyh = w >> 2;
  const int bx = blockIdx.x;
  const int comp = bx & 1;
  const int bh = (bx >> 1) & 31;
  const int p = bx >> 6;            // pair 0..7 -> tiles {p, 15-p}
  const int b = bh >> 4, h = bh & 15;
  const int rowB = b * 2048;
  bf16_t* __restrict__ Obc = comp ? Ob2 : Ob1;

  // ---- staging constants (R7 swizzle lineage; one comp)
  const int lk8 = lane >> 3;               // K: row-within-8
  const int sc8 = (lane & 7) ^ lk8;        // K: pre-swizzled source chunk
  const int lk4 = lane >> 4;               // V: row-within-4
  const int wv = (w - 4) & 3;
  // w<4: wave w stages keys [w*32, w*32+32): 4 gloads of 8 rows (128B rows)
  const size_t kOff = (size_t)(rowB + w * 32 + lk8) * 2048 +
                      comp * 1024 + h * 64 + sc8 * 8;
  // w>=4: wave wv stages d-rows [wv*16, wv*16+16): 4 gloads of 4 rows (256B rows)
  const size_t vOff = ((size_t)b * 2048 + comp * 1024 + h * 64 +
                       wv * 16 + lk4) * 2048;

  auto stage = [&](char* bufb, int j0) {
    if (w < 4) {
      const bf16_t* src = Kg + kOff + (size_t)j0 * 2048;
      char* dst = bufb + w * 4096;
      #pragma unroll
      for (int t = 0; t < 4; ++t)
        gload_lds16(src + (size_t)t * (8 * 2048), (bf16_t*)(dst + t * 1024));
    } else {
      const bf16_t* src = Vtg + vOff + j0;
      char* dst = bufb + 16384 + wv * 4096;
      #pragma unroll
      for (int t = 0; t < 4; ++t) {
        int sc16 = (lane & 15) ^ (((t & 1) << 2) + lk4);
        gload_lds16(src + (size_t)t * (4 * 2048) + sc16 * 8,
                    (bf16_t*)(dst + t * 1024));
      }
    }
  };

  f32x16 o[2];   // [d-half]
  float ls;
  bf16x8 qf[4];

  // ---- phase-end: combine key-half partials (waves 4-7 donate via LDS),
  // normalize by 1/rowsum, store this comp's rows to Obc.
  auto finalize = [&](int q0) {
    float* sf = (float*)ldsbuf;
    __syncthreads();     // compute done; buffer reusable as scratch
    if (w >= 4) {
      float* bp = sf + (size_t)((w - 4) * 64 + lane) * 32;
      #pragma unroll
      for (int e = 0; e < 16; ++e) { bp[e] = o[0][e]; bp[16 + e] = o[1][e]; }
      lsDon[w - 4][lane] = ls;
    }
    __syncthreads();
    if (w < 4) {
      const float* bp = sf + (size_t)(w * 64 + lane) * 32;
      #pragma unroll
      for (int e = 0; e < 16; ++e) { o[0][e] += bp[e]; o[1][e] += bp[16 + e]; }
      ls += lsDon[w][lane];
      float tot = ls + __shfl_xor(ls, 32);
      lsArr[w][l31] = 1.f / tot;
      #pragma unroll
      for (int e = 0; e < 16; ++e) {
        int ql = (e & 3) + 8 * (e >> 2) + 4 * hi;
        float inv = lsArr[w][ql];
        int row = rowB + q0 + w * 32 + ql;
        size_t rb = (size_t)row * 1024 + h * 64 + l31;
        Obc[rb]      = (bf16_t)(o[0][e] * inv);
        Obc[rb + 32] = (bf16_t)(o[1][e] * inv);
      }
    }
  };

  #pragma unroll 1
  for (int i = 0; i <= 16; ++i) {
    const int q0 = (i > p ? 15 - p : p) << 7;
    const int j0 = (i > p ? i - p - 1 : i) << 7;

    __syncthreads();          // everyone done with buffer (compute/finalize)
    stage(ldsbuf, j0);        // async global->LDS

    if (i == 0 || i == p + 1) {  // phase start under staging latency
      #pragma unroll
      for (int s = 0; s < 4; ++s)
        qf[s] = *reinterpret_cast<const bf16x8*>(
            Qg + (size_t)(rowB + q0 + rowg * 32 + l31) * 2048 + comp * 1024 +
            h * 64 + s * 16 + hi * 8);
      o[0] = (f32x16)0.f;
      o[1] = (f32x16)0.f;
      ls = 0.f;
    }

    __syncthreads();          // staged data visible (drains vmcnt)

    const char* bufb = (const char*)ldsbuf;
    const int rowbase = q0 + rowg * 32;
    const int qg = rowbase + l31;
    const bool active = (j0 + keyh * 64) <= (rowbase + 31);
    if (active) {
      const bool maskt = (j0 + keyh * 64 + 63) > rowbase;
      const char* Kb = bufb + keyh * 8192;
      const char* Vb = bufb + 16384;
      // ---- per 32-key half: S' = K Q^T -> P -> pa -> PV
      #pragma unroll
      for (int kb = 0; kb < 2; ++kb) {
        f32x16 sA = {};
        #pragma unroll
        for (int s = 0; s < 4; ++s) {
          int xo = ((2 * s + hi) ^ sw7) << 4;
          bf16x8 kf = *reinterpret_cast<const bf16x8*>(
              Kb + (kb * 32 + l31) * 128 + xo);
          sA = mfma32(kf, qf[s], sA);
        }
        float pv[16];
        #pragma unroll
        for (int e = 0; e < 16; ++e) {
          float v = __builtin_exp2f(sA[e]);   // Q pre-scaled by 0.125*log2e
          if (maskt) {
            int krow = (e & 3) + 8 * (e >> 2) + 4 * hi;
            if (j0 + keyh * 64 + kb * 32 + krow > qg) v = 0.f;
          }
          pv[e] = v;
          ls += v;
        }
        bf16x8 pa[2];
        #pragma unroll
        for (int sp = 0; sp < 2; ++sp) {
          unsigned u0 = pkbf(pv[8 * sp + 0], pv[8 * sp + 1]);
          unsigned u1 = pkbf(pv[8 * sp + 2], pv[8 * sp + 3]);
          unsigned v0 = pkbf(pv[8 * sp + 4], pv[8 * sp + 5]);
          unsigned v1 = pkbf(pv[8 * sp + 6], pv[8 * sp + 7]);
          pl32swap(u0, v0);
          pl32swap(u1, v1);
          union { uint4 u; bf16x8 f; } cvt;
          cvt.u = make_uint4(u0, u1, v0, v1);
          pa[sp] = cvt.f;
        }
        #pragma unroll
        for (int sp = 0; sp < 2; ++sp) {
          int s = kb * 2 + sp;
          int sl = ((keyh * 8) | ((2 * s + hi) ^ sw7)) << 4;
          bf16x8 vf0 = *reinterpret_cast<const bf16x8*>(Vb + l31 * 256 + sl);
          bf16x8 vf1 = *reinterpret_cast<const bf16x8*>(Vb + (32 + l31) * 256 + sl);
          o[0] = mfma32(pa[sp], vf0, o[0]);
          o[1] = mfma32(pa[sp], vf1, o[1]);
        }
      }
    }

    if (i == p || i == 16) finalize(q0);
  }
}

// ---------------------------------------------------------------- launch

extern "C" void kernel_launch(void* const* d_in, const int* in_sizes, int n_in,
                              void* d_out, int out_size, void* d_ws, size_t ws_size,
                              hipStream_t stream) {
  const float* x   = (const float*)d_in[0];
  const float* Wq  = (const float*)d_in[1];
  const float* Wk  = (const float*)d_in[2];
  const float* Wv  = (const float*)d_in[3];
  const float* Wo  = (const float*)d_in[4];
  const float* lq1 = (const float*)d_in[5];
  const float* lk1 = (const float*)d_in[6];
  const float* lq2 = (const float*)d_in[7];
  const float* lk2 = (const float*)d_in[8];
  float* out = (float*)d_out;

  char* ws = (char*)d_ws;
  size_t off = 0;
  auto alloc = [&](size_t bytes) -> char* {
    char* p = ws + off;
    off += (bytes + 255) & ~(size_t)255;
    return p;
  };
  bf16_t* xb  = (bf16_t*)alloc((size_t)4096 * 1024 * 2);
  bf16_t* Wqt = (bf16_t*)alloc((size_t)2048 * 1024 * 2);
  bf16_t* Wkt = (bf16_t*)alloc((size_t)2048 * 1024 * 2);
  bf16_t* Wvt = (bf16_t*)alloc((size_t)2048 * 1024 * 2);
  bf16_t* Wot = (bf16_t*)alloc((size_t)1024 * 1024 * 2);
  bf16_t* Qb  = (bf16_t*)alloc((size_t)4096 * 2048 * 2);
  bf16_t* Kb  = (bf16_t*)alloc((size_t)4096 * 2048 * 2);
  bf16_t* Vtg = (bf16_t*)alloc((size_t)4096 * 2048 * 2);
  bf16_t* Ob  = (bf16_t*)alloc((size_t)4096 * 1024 * 2);
  float*  lamp = (float*)alloc(256);

  // Attn partial outputs alias workspace that is DEAD once gemm_qkv ran and
  // fully rewritten every call (graph-replay safe): Ob1 <- xb (8MB);
  // Ob2 <- Wqt..Wkt (two contiguous 4MB allocs).
  bf16_t* Ob1 = xb;
  bf16_t* Ob2 = Wqt;

  const float QSCALE = 0.125f * 1.44269504088896340736f;  // fold into Wq

  lam_kernel<<<1, 64, 0, stream>>>(lq1, lk1, lq2, lk2, lamp);
  cvt_x_kernel<<<4096, 256, 0, stream>>>(x, xb);
  transpose_cvt<<<dim3(64, 32), dim3(32, 8), 0, stream>>>(Wq, Wqt, 1024, 2048, QSCALE);
  transpose_cvt<<<dim3(64, 32), dim3(32, 8), 0, stream>>>(Wk, Wkt, 1024, 2048, 1.0f);
  transpose_cvt<<<dim3(64, 32), dim3(32, 8), 0, stream>>>(Wv, Wvt, 1024, 2048, 1.0f);
  transpose_cvt<<<dim3(32, 32), dim3(32, 8), 0, stream>>>(Wo, Wot, 1024, 1024, 1.0f);
  gemm_qkv<<<dim3(16, 32, 3), 256, 0, stream>>>(xb, Wqt, Wkt, Wvt, Qb, Kb, Vtg);
  attn_kernel<<<512, 512, 0, stream>>>(Qb, Kb, Vtg, Ob1, Ob2);
  combine_kernel<<<2048, 256, 0, stream>>>(Ob1, Ob2, Ob, lamp);
  gemm_out<<<dim3(8, 32), 256, 0, stream>>>(Ob, Wot, out);
}

// Round 11
// 205.032 us; speedup vs baseline: 1.0580x; 1.0561x over previous
//
#include <hip/hip_runtime.h>
#include <hip/hip_bf16.h>

typedef __bf16 bf16_t;
typedef bf16_t bf16x8 __attribute__((ext_vector_type(8)));
typedef float f32x4 __attribute__((ext_vector_type(4)));
typedef float f32x16 __attribute__((ext_vector_type(16)));

static __device__ __forceinline__ f32x4 mfma16(bf16x8 a, bf16x8 b, f32x4 c) {
  return __builtin_amdgcn_mfma_f32_16x16x32_bf16(a, b, c, 0, 0, 0);
}
static __device__ __forceinline__ f32x16 mfma32(bf16x8 a, bf16x8 b, f32x16 c) {
  return __builtin_amdgcn_mfma_f32_32x32x16_bf16(a, b, c, 0, 0, 0);
}

static __device__ __forceinline__ void gload_lds16(const bf16_t* g, bf16_t* l) {
  __builtin_amdgcn_global_load_lds(
      (const __attribute__((address_space(1))) void*)g,
      (__attribute__((address_space(3))) void*)l, 16, 0, 0);
}

static __device__ __forceinline__ unsigned pkbf(float a, float b) {
  union { bf16_t h[2]; unsigned u; } p;
  p.h[0] = (bf16_t)a; p.h[1] = (bf16_t)b;
  return p.u;
}
static __device__ __forceinline__ void pl32swap(unsigned& a, unsigned& b) {
  asm volatile("v_permlane32_swap_b32 %0, %1" : "+v"(a), "+v"(b));
}

// ---------------------------------------------------------------- tiny kernels

__global__ __launch_bounds__(64) void lam_kernel(const float* __restrict__ lq1,
                                                 const float* __restrict__ lk1,
                                                 const float* __restrict__ lq2,
                                                 const float* __restrict__ lk2,
                                                 float* __restrict__ lamp) {
  int l = threadIdx.x;
  float a = lq1[l] * lk1[l];
  float b = lq2[l] * lk2[l];
  #pragma unroll
  for (int msk = 32; msk; msk >>= 1) {
    a += __shfl_xor(a, msk);
    b += __shfl_xor(b, msk);
  }
  if (l == 0) lamp[0] = __expf(a) - __expf(b) + 0.8f;
}

__global__ __launch_bounds__(256) void cvt_x_kernel(const float* __restrict__ x,
                                                    bf16_t* __restrict__ xb) {
  int i = (blockIdx.x * 256 + threadIdx.x) * 4;
  float4 v = *reinterpret_cast<const float4*>(x + i);
  union { bf16_t h[4]; uint2 u; } pk;
  pk.h[0] = (bf16_t)v.x; pk.h[1] = (bf16_t)v.y;
  pk.h[2] = (bf16_t)v.z; pk.h[3] = (bf16_t)v.w;
  *reinterpret_cast<uint2*>(xb + i) = pk.u;
}

// W: [K][N] fp32 row-major  ->  Wt: [N][K] bf16 row-major, scaled
__global__ __launch_bounds__(256) void transpose_cvt(const float* __restrict__ W,
                                                     bf16_t* __restrict__ Wt,
                                                     int K, int N, float scale) {
  __shared__ float tile[32][33];
  int n0 = blockIdx.x * 32, k0 = blockIdx.y * 32;
  int x = threadIdx.x, y = threadIdx.y;  // 32 x 8
  #pragma unroll
  for (int i = 0; i < 32; i += 8)
    tile[y + i][x] = W[(size_t)(k0 + y + i) * N + n0 + x];
  __syncthreads();
  #pragma unroll
  for (int i = 0; i < 32; i += 8)
    Wt[(size_t)(n0 + y + i) * K + k0 + x] = (bf16_t)(tile[x][y + i] * scale);
}

// ---------------------------------------------------------------- GEMM (A[M][K] x Bt[N][K]^T)

template <typename OutT>
static __device__ __forceinline__ void gemm_bt_body(const bf16_t* __restrict__ A,
                                                    const bf16_t* __restrict__ Bt,
                                                    OutT* __restrict__ C,
                                                    int M, int N, int K,
                                                    bool vtrans) {
  __shared__ bf16_t As[128 * 32];
  __shared__ bf16_t Bs[128 * 32];
  const int tid = threadIdx.x;
  const int w = tid >> 6, lane = tid & 63;
  const int g = lane >> 4, l15 = lane & 15;
  const int wm = w >> 1, wn = w & 1;

  // T1: XCD-contiguous block swizzle (n = gridDim.x*gridDim.y divisible by 8)
  const int nbx = gridDim.x;
  const int idx = blockIdx.y * nbx + blockIdx.x;
  const int qq = (nbx * gridDim.y) >> 3;
  const int sidx = (idx & 7) * qq + (idx >> 3);
  const int rowBase = (sidx / nbx) * 128, colBase = (sidx % nbx) * 128;

  const int c0 = 2 * w, c1 = 2 * w + 1;
  const int srow0 = 16 * c0 + (lane >> 2);
  const int srow1 = 16 * c1 + (lane >> 2);
  const int scol = (lane & 3) * 8;

  f32x4 acc[4][4] = {};

  for (int k0 = 0; k0 < K; k0 += 32) {
    __syncthreads();
    gload_lds16(A + (size_t)(rowBase + srow0) * K + k0 + scol, &As[c0 * 512]);
    gload_lds16(A + (size_t)(rowBase + srow1) * K + k0 + scol, &As[c1 * 512]);
    gload_lds16(Bt + (size_t)(colBase + srow0) * K + k0 + scol, &Bs[c0 * 512]);
    gload_lds16(Bt + (size_t)(colBase + srow1) * K + k0 + scol, &Bs[c1 * 512]);
    __syncthreads();

    bf16x8 bfr[4];
    #pragma unroll
    for (int j = 0; j < 4; ++j)
      bfr[j] = *reinterpret_cast<const bf16x8*>(&Bs[(wn * 64 + j * 16 + l15) * 32 + g * 8]);
    #pragma unroll
    for (int i = 0; i < 4; ++i) {
      bf16x8 afr = *reinterpret_cast<const bf16x8*>(&As[(wm * 64 + i * 16 + l15) * 32 + g * 8]);
      #pragma unroll
      for (int j = 0; j < 4; ++j)
        acc[i][j] = mfma16(afr, bfr[j], acc[i][j]);
    }
  }

  if (vtrans) {
    #pragma unroll
    for (int i = 0; i < 4; ++i) {
      #pragma unroll
      for (int j = 0; j < 4; ++j) {
        int row = rowBase + wm * 64 + i * 16 + 4 * g;  // global s in [0,4096)
        int col = colBase + wn * 64 + j * 16 + l15;    // [0,2048)
        int bb = row >> 11, s = row & 2047;
        union { bf16_t h[4]; uint2 u; } pk;
        #pragma unroll
        for (int r = 0; r < 4; ++r) pk.h[r] = (bf16_t)acc[i][j][r];
        *reinterpret_cast<uint2*>(
            (bf16_t*)C + ((size_t)bb * 2048 + col) * 2048 + s) = pk.u;
      }
    }
  } else {
    #pragma unroll
    for (int i = 0; i < 4; ++i) {
      #pragma unroll
      for (int j = 0; j < 4; ++j) {
        int row = rowBase + wm * 64 + i * 16 + 4 * g;
        int col = colBase + wn * 64 + j * 16 + l15;
        #pragma unroll
        for (int r = 0; r < 4; ++r)
          C[(size_t)(row + r) * N + col] = (OutT)acc[i][j][r];
      }
    }
  }
}

__global__ __launch_bounds__(256) void gemm_qkv(const bf16_t* __restrict__ xb,
                                                const bf16_t* __restrict__ Wqt,
                                                const bf16_t* __restrict__ Wkt,
                                                const bf16_t* __restrict__ Wvt,
                                                bf16_t* __restrict__ Q,
                                                bf16_t* __restrict__ K,
                                                bf16_t* __restrict__ Vtg) {
  const bf16_t* Bt = (blockIdx.z == 0) ? Wqt : (blockIdx.z == 1) ? Wkt : Wvt;
  bf16_t* C = (blockIdx.z == 0) ? Q : (blockIdx.z == 1) ? K : Vtg;
  gemm_bt_body<bf16_t>(xb, Bt, C, 4096, 2048, 1024, blockIdx.z == 2);
}

__global__ __launch_bounds__(256) void gemm_out(const bf16_t* __restrict__ Ob,
                                                const bf16_t* __restrict__ Wot,
                                                float* __restrict__ out) {
  gemm_bt_body<float>(Ob, Wot, out, 4096, 1024, 1024, false);
}

// ---------------------------------------------------------------- attention
// R7 structure VERBATIM (verified, 98.3us) with three surgical edits:
// (a) Q pre-scaled by 0.125*log2e folded into Wqt (R8/R9-verified) -> exp2
//     takes sA raw, deleting 64 v_mul per iter;
// (b) row-sum via ones-B MFMA: lsum[comp] = mfma(pa, ones, lsum) has the SAME
//     C-layout as o (rows = crow(e,hi)) and sums the step's full K=16 ->
//     deletes the serial 64-add/iter ls chain + lsArr/shfl broadcast;
// (c) T5 s_setprio(1) around the QK^T and PV MFMA clusters.
// 256 blocks x 512 thr (8 waves), 1 block/CU (grid=#CU), KVBLK=128,
// pair {p,15-p} sequential = 17 iters. VGPR grows ~+30 (lsum) - free at
// 2 waves/SIMD. LDS (64KB): K [comp*128+key][128B swz] | V +32KB [comp*64+d][256B swz].

__global__ __launch_bounds__(512, 1)
void attn_kernel(const bf16_t* __restrict__ Qg, const bf16_t* __restrict__ Kg,
                 const bf16_t* __restrict__ Vtg, bf16_t* __restrict__ Og,
                 const float* __restrict__ lamp) {
  __shared__ __align__(16) char ldsbuf[65536];

  const int tid = threadIdx.x;
  const int w = tid >> 6, lane = tid & 63;
  const int l31 = lane & 31, hi = lane >> 5;
  const int sw7 = l31 & 7;
  const int rowg = w & 3, keyh = w >> 2;
  const int bx = blockIdx.x;
  const int p = bx >> 5;            // pair 0..7 -> tiles {p, 15-p}
  const int bh = bx & 31;
  const int b = bh >> 4, h = bh & 15;
  const int rowB = b * 2048;
  const float lam = *lamp;

  const bf16_t one = (bf16_t)1.0f;
  const bf16x8 ones = {one, one, one, one, one, one, one, one};

  // ---- staging constants (verbatim R3/R4/R7 lineage)
  const int lk8 = lane >> 3;               // K: row-within-8
  const int sc8 = (lane & 7) ^ lk8;        // K: pre-swizzled source chunk
  const int lk4 = lane >> 4;               // V: row-within-4
  const int wv = (w - 4) & 3;
  const size_t kOff = (size_t)(rowB + ((w & 1) << 6) + lk8) * 2048 +
                      (w >> 1) * 1024 + h * 64 + sc8 * 8;           // w<4
  const size_t vOff = ((size_t)b * 2048 + (wv >> 1) * 1024 + h * 64 +
                       ((wv & 1) << 5) + lk4) * 2048;               // w>=4

  auto stage = [&](char* bufb, int j0) {
    if (w < 4) {
      const bf16_t* src = Kg + kOff + (size_t)j0 * 2048;
      char* dst = bufb + w * 8192;
      #pragma unroll
      for (int t = 0; t < 8; ++t)
        gload_lds16(src + (size_t)t * (8 * 2048), (bf16_t*)(dst + t * 1024));
    } else {
      const bf16_t* src = Vtg + vOff + j0;
      char* dst = bufb + 32768 + wv * 8192;
      #pragma unroll
      for (int t = 0; t < 8; ++t) {
        int sc16 = (lane & 15) ^ (((t & 1) << 2) + lk4);
        gload_lds16(src + (size_t)t * (4 * 2048) + sc16 * 8,
                    (bf16_t*)(dst + t * 1024));
      }
    }
  };

  f32x16 o[2][2];
  f32x16 lsum[2];
  bf16x8 qf[2][4];

  // ---- phase-end: combine key-half partials (o AND lsum) via freed LDS
  // buffer; waves 4-7 donate, waves 0-3 add, normalize per-element, store.
  auto finalize = [&](int q0, char* scratch) {
    float* sf = (float*)scratch;
    #pragma unroll
    for (int rd = 0; rd < 4; ++rd) {
      const int comp = rd >> 1, db = rd & 1;
      __syncthreads();
      if (w >= 4) {
        float* bp = sf + (size_t)((w - 4) * 64 + lane) * 32;
        #pragma unroll
        for (int e = 0; e < 16; ++e) bp[e] = o[comp][db][e];
        if (db == 0) {
          #pragma unroll
          for (int e = 0; e < 16; ++e) bp[16 + e] = lsum[comp][e];
        }
      }
      __syncthreads();
      if (w < 4) {
        const float* bp = sf + (size_t)(w * 64 + lane) * 32;
        #pragma unroll
        for (int e = 0; e < 16; ++e) o[comp][db][e] += bp[e];
        if (db == 0) {
          #pragma unroll
          for (int e = 0; e < 16; ++e) lsum[comp][e] += bp[16 + e];
        }
      }
    }
    __syncthreads();  // scratch reads done
    if (w < 4) {
      #pragma unroll
      for (int e = 0; e < 16; ++e) {
        int ql = (e & 3) + 8 * (e >> 2) + 4 * hi;
        float i1 = 1.f / lsum[0][e];
        float i2 = lam / lsum[1][e];
        int row = rowB + q0 + w * 32 + ql;
        size_t rb = (size_t)row * 1024 + h * 64 + l31;
        Og[rb]      = (bf16_t)((o[0][0][e] * i1 - o[1][0][e] * i2) * 0.2f);
        Og[rb + 32] = (bf16_t)((o[0][1][e] * i1 - o[1][1][e] * i2) * 0.2f);
      }
    }
  };

  #pragma unroll 1
  for (int i = 0; i <= 16; ++i) {
    const int q0 = (i > p ? 15 - p : p) << 7;
    const int j0 = (i > p ? i - p - 1 : i) << 7;

    __syncthreads();          // everyone done with buffer (compute/finalize)
    stage(ldsbuf, j0);        // async global->LDS

    if (i == 0 || i == p + 1) {  // phase start under staging latency
      #pragma unroll
      for (int comp = 0; comp < 2; ++comp)
        #pragma unroll
        for (int s = 0; s < 4; ++s)
          qf[comp][s] = *reinterpret_cast<const bf16x8*>(
              Qg + (size_t)(rowB + q0 + rowg * 32 + l31) * 2048 + comp * 1024 +
              h * 64 + s * 16 + hi * 8);
      #pragma unroll
      for (int comp = 0; comp < 2; ++comp) {
        o[comp][0] = (f32x16)0.f;
        o[comp][1] = (f32x16)0.f;
        lsum[comp] = (f32x16)0.f;
      }
    }

    __syncthreads();          // staged data visible (drains vmcnt)

    const char* bufb = (const char*)ldsbuf;
    const int rowbase = q0 + rowg * 32;
    const int qg = rowbase + l31;
    const bool active = (j0 + keyh * 64) <= (rowbase + 31);
    if (active) {
      const bool maskt = (j0 + keyh * 64 + 63) > rowbase;
      #pragma unroll
      for (int comp = 0; comp < 2; ++comp) {
        const char* Kb = bufb + comp * 16384 + keyh * 64 * 128;
        const char* Vb = bufb + 32768 + comp * 16384;
        // ---- per 32-key half: S' = K Q^T -> P -> pa -> PV + lsum
        #pragma unroll
        for (int kb = 0; kb < 2; ++kb) {
          f32x16 sA = {};
          __builtin_amdgcn_s_setprio(1);
          #pragma unroll
          for (int s = 0; s < 4; ++s) {
            int xo = ((2 * s + hi) ^ sw7) << 4;
            bf16x8 kf = *reinterpret_cast<const bf16x8*>(
                Kb + (kb * 32 + l31) * 128 + xo);
            sA = mfma32(kf, qf[comp][s], sA);
          }
          __builtin_amdgcn_s_setprio(0);
          float pv[16];
          #pragma unroll
          for (int e = 0; e < 16; ++e) {
            float v = __builtin_exp2f(sA[e]);   // Q pre-scaled by 0.125*log2e
            if (maskt) {
              int krow = (e & 3) + 8 * (e >> 2) + 4 * hi;
              if (j0 + keyh * 64 + kb * 32 + krow > qg) v = 0.f;
            }
            pv[e] = v;
          }
          bf16x8 pa[2];
          #pragma unroll
          for (int sp = 0; sp < 2; ++sp) {
            unsigned u0 = pkbf(pv[8 * sp + 0], pv[8 * sp + 1]);
            unsigned u1 = pkbf(pv[8 * sp + 2], pv[8 * sp + 3]);
            unsigned v0 = pkbf(pv[8 * sp + 4], pv[8 * sp + 5]);
            unsigned v1 = pkbf(pv[8 * sp + 6], pv[8 * sp + 7]);
            pl32swap(u0, v0);
            pl32swap(u1, v1);
            union { uint4 u; bf16x8 f; } cvt;
            cvt.u = make_uint4(u0, u1, v0, v1);
            pa[sp] = cvt.f;
          }
          __builtin_amdgcn_s_setprio(1);
          #pragma unroll
          for (int sp = 0; sp < 2; ++sp) {
            int s = kb * 2 + sp;
            int sl = ((keyh * 8) | ((2 * s + hi) ^ sw7)) << 4;
            bf16x8 vf0 = *reinterpret_cast<const bf16x8*>(Vb + l31 * 256 + sl);
            bf16x8 vf1 = *reinterpret_cast<const bf16x8*>(Vb + (32 + l31) * 256 + sl);
            o[comp][0] = mfma32(pa[sp], vf0, o[comp][0]);
            o[comp][1] = mfma32(pa[sp], vf1, o[comp][1]);
            lsum[comp] = mfma32(pa[sp], ones, lsum[comp]);
          }
          __builtin_amdgcn_s_setprio(0);
        }
      }
    }

    if (i == p || i == 16) finalize(q0, ldsbuf);
  }
}

// ---------------------------------------------------------------- launch

extern "C" void kernel_launch(void* const* d_in, const int* in_sizes, int n_in,
                              void* d_out, int out_size, void* d_ws, size_t ws_size,
                              hipStream_t stream) {
  const float* x   = (const float*)d_in[0];
  const float* Wq  = (const float*)d_in[1];
  const float* Wk  = (const float*)d_in[2];
  const float* Wv  = (const float*)d_in[3];
  const float* Wo  = (const float*)d_in[4];
  const float* lq1 = (const float*)d_in[5];
  const float* lk1 = (const float*)d_in[6];
  const float* lq2 = (const float*)d_in[7];
  const float* lk2 = (const float*)d_in[8];
  float* out = (float*)d_out;

  char* ws = (char*)d_ws;
  size_t off = 0;
  auto alloc = [&](size_t bytes) -> char* {
    char* p = ws + off;
    off += (bytes + 255) & ~(size_t)255;
    return p;
  };
  bf16_t* xb  = (bf16_t*)alloc((size_t)4096 * 1024 * 2);
  bf16_t* Wqt = (bf16_t*)alloc((size_t)2048 * 1024 * 2);
  bf16_t* Wkt = (bf16_t*)alloc((size_t)2048 * 1024 * 2);
  bf16_t* Wvt = (bf16_t*)alloc((size_t)2048 * 1024 * 2);
  bf16_t* Wot = (bf16_t*)alloc((size_t)1024 * 1024 * 2);
  bf16_t* Qb  = (bf16_t*)alloc((size_t)4096 * 2048 * 2);
  bf16_t* Kb  = (bf16_t*)alloc((size_t)4096 * 2048 * 2);
  bf16_t* Vtg = (bf16_t*)alloc((size_t)4096 * 2048 * 2);
  bf16_t* Ob  = (bf16_t*)alloc((size_t)4096 * 1024 * 2);
  float*  lamp = (float*)alloc(256);

  const float QSCALE = 0.125f * 1.44269504088896340736f;  // fold into Wq

  lam_kernel<<<1, 64, 0, stream>>>(lq1, lk1, lq2, lk2, lamp);
  cvt_x_kernel<<<4096, 256, 0, stream>>>(x, xb);
  transpose_cvt<<<dim3(64, 32), dim3(32, 8), 0, stream>>>(Wq, Wqt, 1024, 2048, QSCALE);
  transpose_cvt<<<dim3(64, 32), dim3(32, 8), 0, stream>>>(Wk, Wkt, 1024, 2048, 1.0f);
  transpose_cvt<<<dim3(64, 32), dim3(32, 8), 0, stream>>>(Wv, Wvt, 1024, 2048, 1.0f);
  transpose_cvt<<<dim3(32, 32), dim3(32, 8), 0, stream>>>(Wo, Wot, 1024, 1024, 1.0f);
  gemm_qkv<<<dim3(16, 32, 3), 256, 0, stream>>>(xb, Wqt, Wkt, Wvt, Qb, Kb, Vtg);
  attn_kernel<<<256, 512, 0, stream>>>(Qb, Kb, Vtg, Ob, lamp);
  gemm_out<<<dim3(8, 32), 256, 0, stream>>>(Ob, Wot, out);
}

// Round 12
// 190.103 us; speedup vs baseline: 1.1411x; 1.0785x over previous
//
#include <hip/hip_runtime.h>
#include <hip/hip_bf16.h>

typedef __bf16 bf16_t;
typedef bf16_t bf16x8 __attribute__((ext_vector_type(8)));
typedef float f32x4 __attribute__((ext_vector_type(4)));
typedef float f32x16 __attribute__((ext_vector_type(16)));

static __device__ __forceinline__ f32x4 mfma16(bf16x8 a, bf16x8 b, f32x4 c) {
  return __builtin_amdgcn_mfma_f32_16x16x32_bf16(a, b, c, 0, 0, 0);
}
static __device__ __forceinline__ f32x16 mfma32(bf16x8 a, bf16x8 b, f32x16 c) {
  return __builtin_amdgcn_mfma_f32_32x32x16_bf16(a, b, c, 0, 0, 0);
}

static __device__ __forceinline__ void gload_lds16(const bf16_t* g, bf16_t* l) {
  __builtin_amdgcn_global_load_lds(
      (const __attribute__((address_space(1))) void*)g,
      (__attribute__((address_space(3))) void*)l, 16, 0, 0);
}

static __device__ __forceinline__ unsigned pkbf(float a, float b) {
  union { bf16_t h[2]; unsigned u; } p;
  p.h[0] = (bf16_t)a; p.h[1] = (bf16_t)b;
  return p.u;
}
static __device__ __forceinline__ void pl32swap(unsigned& a, unsigned& b) {
  asm volatile("v_permlane32_swap_b32 %0, %1" : "+v"(a), "+v"(b));
}

// ---------------------------------------------------------------- tiny kernels

__global__ __launch_bounds__(256) void cvt_x_kernel(const float* __restrict__ x,
                                                    bf16_t* __restrict__ xb) {
  int i = (blockIdx.x * 256 + threadIdx.x) * 4;
  float4 v = *reinterpret_cast<const float4*>(x + i);
  union { bf16_t h[4]; uint2 u; } pk;
  pk.h[0] = (bf16_t)v.x; pk.h[1] = (bf16_t)v.y;
  pk.h[2] = (bf16_t)v.z; pk.h[3] = (bf16_t)v.w;
  *reinterpret_cast<uint2*>(xb + i) = pk.u;
}

// All four weight transposes fused: W [1024][N] fp32 -> Wt [N][1024] bf16.
// z: 0=Wq(scaled) 1=Wk 2=Wv 3=Wo(N=1024, half the x-grid).
__global__ __launch_bounds__(256) void transpose_cvt_all(
    const float* __restrict__ Wq, const float* __restrict__ Wk,
    const float* __restrict__ Wv, const float* __restrict__ Wo,
    bf16_t* __restrict__ Wqt, bf16_t* __restrict__ Wkt,
    bf16_t* __restrict__ Wvt, bf16_t* __restrict__ Wot, float qscale) {
  __shared__ float tile[32][33];
  const int z = blockIdx.z;
  const float* W; bf16_t* Wt; int N; float scale = 1.0f;
  if (z == 0)      { W = Wq; Wt = Wqt; N = 2048; scale = qscale; }
  else if (z == 1) { W = Wk; Wt = Wkt; N = 2048; }
  else if (z == 2) { W = Wv; Wt = Wvt; N = 2048; }
  else             { W = Wo; Wt = Wot; N = 1024; if (blockIdx.x >= 32) return; }
  const int K = 1024;
  int n0 = blockIdx.x * 32, k0 = blockIdx.y * 32;
  int x = threadIdx.x, y = threadIdx.y;  // 32 x 8
  #pragma unroll
  for (int i = 0; i < 32; i += 8)
    tile[y + i][x] = W[(size_t)(k0 + y + i) * N + n0 + x];
  __syncthreads();
  #pragma unroll
  for (int i = 0; i < 32; i += 8)
    Wt[(size_t)(n0 + y + i) * K + k0 + x] = (bf16_t)(tile[x][y + i] * scale);
}

// ---------------------------------------------------------------- GEMM (A[M][K] x Bt[N][K]^T)

template <typename OutT>
static __device__ __forceinline__ void gemm_bt_body(const bf16_t* __restrict__ A,
                                                    const bf16_t* __restrict__ Bt,
                                                    OutT* __restrict__ C,
                                                    int M, int N, int K,
                                                    bool vtrans) {
  __shared__ bf16_t As[128 * 32];
  __shared__ bf16_t Bs[128 * 32];
  const int tid = threadIdx.x;
  const int w = tid >> 6, lane = tid & 63;
  const int g = lane >> 4, l15 = lane & 15;
  const int wm = w >> 1, wn = w & 1;

  // T1: XCD-contiguous block swizzle (n = gridDim.x*gridDim.y divisible by 8)
  const int nbx = gridDim.x;
  const int idx = blockIdx.y * nbx + blockIdx.x;
  const int qq = (nbx * gridDim.y) >> 3;
  const int sidx = (idx & 7) * qq + (idx >> 3);
  const int rowBase = (sidx / nbx) * 128, colBase = (sidx % nbx) * 128;

  const int c0 = 2 * w, c1 = 2 * w + 1;
  const int srow0 = 16 * c0 + (lane >> 2);
  const int srow1 = 16 * c1 + (lane >> 2);
  const int scol = (lane & 3) * 8;

  f32x4 acc[4][4] = {};

  for (int k0 = 0; k0 < K; k0 += 32) {
    __syncthreads();
    gload_lds16(A + (size_t)(rowBase + srow0) * K + k0 + scol, &As[c0 * 512]);
    gload_lds16(A + (size_t)(rowBase + srow1) * K + k0 + scol, &As[c1 * 512]);
    gload_lds16(Bt + (size_t)(colBase + srow0) * K + k0 + scol, &Bs[c0 * 512]);
    gload_lds16(Bt + (size_t)(colBase + srow1) * K + k0 + scol, &Bs[c1 * 512]);
    __syncthreads();

    bf16x8 bfr[4];
    #pragma unroll
    for (int j = 0; j < 4; ++j)
      bfr[j] = *reinterpret_cast<const bf16x8*>(&Bs[(wn * 64 + j * 16 + l15) * 32 + g * 8]);
    #pragma unroll
    for (int i = 0; i < 4; ++i) {
      bf16x8 afr = *reinterpret_cast<const bf16x8*>(&As[(wm * 64 + i * 16 + l15) * 32 + g * 8]);
      #pragma unroll
      for (int j = 0; j < 4; ++j)
        acc[i][j] = mfma16(afr, bfr[j], acc[i][j]);
    }
  }

  if (vtrans) {
    #pragma unroll
    for (int i = 0; i < 4; ++i) {
      #pragma unroll
      for (int j = 0; j < 4; ++j) {
        int row = rowBase + wm * 64 + i * 16 + 4 * g;  // global s in [0,4096)
        int col = colBase + wn * 64 + j * 16 + l15;    // [0,2048)
        int bb = row >> 11, s = row & 2047;
        union { bf16_t h[4]; uint2 u; } pk;
        #pragma unroll
        for (int r = 0; r < 4; ++r) pk.h[r] = (bf16_t)acc[i][j][r];
        *reinterpret_cast<uint2*>(
            (bf16_t*)C + ((size_t)bb * 2048 + col) * 2048 + s) = pk.u;
      }
    }
  } else {
    #pragma unroll
    for (int i = 0; i < 4; ++i) {
      #pragma unroll
      for (int j = 0; j < 4; ++j) {
        int row = rowBase + wm * 64 + i * 16 + 4 * g;
        int col = colBase + wn * 64 + j * 16 + l15;
        #pragma unroll
        for (int r = 0; r < 4; ++r)
          C[(size_t)(row + r) * N + col] = (OutT)acc[i][j][r];
      }
    }
  }
}

__global__ __launch_bounds__(256) void gemm_qkv(const bf16_t* __restrict__ xb,
                                                const bf16_t* __restrict__ Wqt,
                                                const bf16_t* __restrict__ Wkt,
                                                const bf16_t* __restrict__ Wvt,
                                                bf16_t* __restrict__ Q,
                                                bf16_t* __restrict__ K,
                                                bf16_t* __restrict__ Vtg) {
  const bf16_t* Bt = (blockIdx.z == 0) ? Wqt : (blockIdx.z == 1) ? Wkt : Wvt;
  bf16_t* C = (blockIdx.z == 0) ? Q : (blockIdx.z == 1) ? K : Vtg;
  gemm_bt_body<bf16_t>(xb, Bt, C, 4096, 2048, 1024, blockIdx.z == 2);
}

__global__ __launch_bounds__(256) void gemm_out(const bf16_t* __restrict__ Ob,
                                                const bf16_t* __restrict__ Wot,
                                                float* __restrict__ out) {
  gemm_bt_body<float>(Ob, Wot, out, 4096, 1024, 1024, false);
}

// ---------------------------------------------------------------- attention
// R11 structure with the finalize bank-conflict REGRESSION FIXED: scratch
// stride 32 floats (128B -> all 64 lanes same bank, 64-way serialize; the
// +4.1M conflicts that made R11 slower than R7) -> 33 floats (33 coprime 32,
// conflict-free). lam is computed in-kernel (per-wave 64-wide dot, ~40cy) --
// deletes the lam_kernel launch. Everything else verbatim R11:
// 256 blocks x 512 thr, 1 block/CU, KVBLK=128, pair {p,15-p} = 17 iters;
// Q pre-scaled by 0.125*log2e in Wqt; rowsum via ones-B MFMA; T5 setprio.
// LDS (64KB): K [comp*128+key][128B swz] | V +32KB [comp*64+d][256B swz].

__global__ __launch_bounds__(512, 1)
void attn_kernel(const bf16_t* __restrict__ Qg, const bf16_t* __restrict__ Kg,
                 const bf16_t* __restrict__ Vtg, bf16_t* __restrict__ Og,
                 const float* __restrict__ lq1, const float* __restrict__ lk1,
                 const float* __restrict__ lq2, const float* __restrict__ lk2) {
  __shared__ __align__(16) char ldsbuf[65536];

  const int tid = threadIdx.x;
  const int w = tid >> 6, lane = tid & 63;
  const int l31 = lane & 31, hi = lane >> 5;
  const int sw7 = l31 & 7;
  const int rowg = w & 3, keyh = w >> 2;
  const int bx = blockIdx.x;
  const int p = bx >> 5;            // pair 0..7 -> tiles {p, 15-p}
  const int bh = bx & 31;
  const int b = bh >> 4, h = bh & 15;
  const int rowB = b * 2048;

  // ---- lambda, computed per-wave (replaces lam_kernel)
  float lam;
  {
    float a = lq1[lane] * lk1[lane];
    float c = lq2[lane] * lk2[lane];
    #pragma unroll
    for (int msk = 32; msk; msk >>= 1) {
      a += __shfl_xor(a, msk);
      c += __shfl_xor(c, msk);
    }
    lam = __expf(a) - __expf(c) + 0.8f;
  }

  const bf16_t one = (bf16_t)1.0f;
  const bf16x8 ones = {one, one, one, one, one, one, one, one};

  // ---- staging constants (verbatim R3/R4/R7 lineage)
  const int lk8 = lane >> 3;               // K: row-within-8
  const int sc8 = (lane & 7) ^ lk8;        // K: pre-swizzled source chunk
  const int lk4 = lane >> 4;               // V: row-within-4
  const int wv = (w - 4) & 3;
  const size_t kOff = (size_t)(rowB + ((w & 1) << 6) + lk8) * 2048 +
                      (w >> 1) * 1024 + h * 64 + sc8 * 8;           // w<4
  const size_t vOff = ((size_t)b * 2048 + (wv >> 1) * 1024 + h * 64 +
                       ((wv & 1) << 5) + lk4) * 2048;               // w>=4

  auto stage = [&](char* bufb, int j0) {
    if (w < 4) {
      const bf16_t* src = Kg + kOff + (size_t)j0 * 2048;
      char* dst = bufb + w * 8192;
      #pragma unroll
      for (int t = 0; t < 8; ++t)
        gload_lds16(src + (size_t)t * (8 * 2048), (bf16_t*)(dst + t * 1024));
    } else {
      const bf16_t* src = Vtg + vOff + j0;
      char* dst = bufb + 32768 + wv * 8192;
      #pragma unroll
      for (int t = 0; t < 8; ++t) {
        int sc16 = (lane & 15) ^ (((t & 1) << 2) + lk4);
        gload_lds16(src + (size_t)t * (4 * 2048) + sc16 * 8,
                    (bf16_t*)(dst + t * 1024));
      }
    }
  };

  f32x16 o[2][2];
  f32x16 lsum[2];
  bf16x8 qf[2][4];

  // ---- phase-end: combine key-half partials (o AND lsum) via freed LDS
  // buffer; stride 33 floats (conflict-free: 33 coprime 32). Waves 4-7
  // donate, waves 0-3 add, normalize per-element, store.
  auto finalize = [&](int q0, char* scratch) {
    float* sf = (float*)scratch;
    #pragma unroll
    for (int rd = 0; rd < 4; ++rd) {
      const int comp = rd >> 1, db = rd & 1;
      __syncthreads();
      if (w >= 4) {
        float* bp = sf + (size_t)((w - 4) * 64 + lane) * 33;
        #pragma unroll
        for (int e = 0; e < 16; ++e) bp[e] = o[comp][db][e];
        if (db == 0) {
          #pragma unroll
          for (int e = 0; e < 16; ++e) bp[16 + e] = lsum[comp][e];
        }
      }
      __syncthreads();
      if (w < 4) {
        const float* bp = sf + (size_t)(w * 64 + lane) * 33;
        #pragma unroll
        for (int e = 0; e < 16; ++e) o[comp][db][e] += bp[e];
        if (db == 0) {
          #pragma unroll
          for (int e = 0; e < 16; ++e) lsum[comp][e] += bp[16 + e];
        }
      }
    }
    __syncthreads();  // scratch reads done
    if (w < 4) {
      #pragma unroll
      for (int e = 0; e < 16; ++e) {
        int ql = (e & 3) + 8 * (e >> 2) + 4 * hi;
        float i1 = 1.f / lsum[0][e];
        float i2 = lam / lsum[1][e];
        int row = rowB + q0 + w * 32 + ql;
        size_t rb = (size_t)row * 1024 + h * 64 + l31;
        Og[rb]      = (bf16_t)((o[0][0][e] * i1 - o[1][0][e] * i2) * 0.2f);
        Og[rb + 32] = (bf16_t)((o[0][1][e] * i1 - o[1][1][e] * i2) * 0.2f);
      }
    }
  };

  #pragma unroll 1
  for (int i = 0; i <= 16; ++i) {
    const int q0 = (i > p ? 15 - p : p) << 7;
    const int j0 = (i > p ? i - p - 1 : i) << 7;

    __syncthreads();          // everyone done with buffer (compute/finalize)
    stage(ldsbuf, j0);        // async global->LDS

    if (i == 0 || i == p + 1) {  // phase start under staging latency
      #pragma unroll
      for (int comp = 0; comp < 2; ++comp)
        #pragma unroll
        for (int s = 0; s < 4; ++s)
          qf[comp][s] = *reinterpret_cast<const bf16x8*>(
              Qg + (size_t)(rowB + q0 + rowg * 32 + l31) * 2048 + comp * 1024 +
              h * 64 + s * 16 + hi * 8);
      #pragma unroll
      for (int comp = 0; comp < 2; ++comp) {
        o[comp][0] = (f32x16)0.f;
        o[comp][1] = (f32x16)0.f;
        lsum[comp] = (f32x16)0.f;
      }
    }

    __syncthreads();          // staged data visible (drains vmcnt)

    const char* bufb = (const char*)ldsbuf;
    const int rowbase = q0 + rowg * 32;
    const int qg = rowbase + l31;
    const bool active = (j0 + keyh * 64) <= (rowbase + 31);
    if (active) {
      const bool maskt = (j0 + keyh * 64 + 63) > rowbase;
      #pragma unroll
      for (int comp = 0; comp < 2; ++comp) {
        const char* Kb = bufb + comp * 16384 + keyh * 64 * 128;
        const char* Vb = bufb + 32768 + comp * 16384;
        // ---- per 32-key half: S' = K Q^T -> P -> pa -> PV + lsum
        #pragma unroll
        for (int kb = 0; kb < 2; ++kb) {
          f32x16 sA = {};
          __builtin_amdgcn_s_setprio(1);
          #pragma unroll
          for (int s = 0; s < 4; ++s) {
            int xo = ((2 * s + hi) ^ sw7) << 4;
            bf16x8 kf = *reinterpret_cast<const bf16x8*>(
                Kb + (kb * 32 + l31) * 128 + xo);
            sA = mfma32(kf, qf[comp][s], sA);
          }
          __builtin_amdgcn_s_setprio(0);
          float pv[16];
          #pragma unroll
          for (int e = 0; e < 16; ++e) {
            float v = __builtin_exp2f(sA[e]);   // Q pre-scaled by 0.125*log2e
            if (maskt) {
              int krow = (e & 3) + 8 * (e >> 2) + 4 * hi;
              if (j0 + keyh * 64 + kb * 32 + krow > qg) v = 0.f;
            }
            pv[e] = v;
          }
          bf16x8 pa[2];
          #pragma unroll
          for (int sp = 0; sp < 2; ++sp) {
            unsigned u0 = pkbf(pv[8 * sp + 0], pv[8 * sp + 1]);
            unsigned u1 = pkbf(pv[8 * sp + 2], pv[8 * sp + 3]);
            unsigned v0 = pkbf(pv[8 * sp + 4], pv[8 * sp + 5]);
            unsigned v1 = pkbf(pv[8 * sp + 6], pv[8 * sp + 7]);
            pl32swap(u0, v0);
            pl32swap(u1, v1);
            union { uint4 u; bf16x8 f; } cvt;
            cvt.u = make_uint4(u0, u1, v0, v1);
            pa[sp] = cvt.f;
          }
          __builtin_amdgcn_s_setprio(1);
          #pragma unroll
          for (int sp = 0; sp < 2; ++sp) {
            int s = kb * 2 + sp;
            int sl = ((keyh * 8) | ((2 * s + hi) ^ sw7)) << 4;
            bf16x8 vf0 = *reinterpret_cast<const bf16x8*>(Vb + l31 * 256 + sl);
            bf16x8 vf1 = *reinterpret_cast<const bf16x8*>(Vb + (32 + l31) * 256 + sl);
            o[comp][0] = mfma32(pa[sp], vf0, o[comp][0]);
            o[comp][1] = mfma32(pa[sp], vf1, o[comp][1]);
            lsum[comp] = mfma32(pa[sp], ones, lsum[comp]);
          }
          __builtin_amdgcn_s_setprio(0);
        }
      }
    }

    if (i == p || i == 16) finalize(q0, ldsbuf);
  }
}

// ---------------------------------------------------------------- launch

extern "C" void kernel_launch(void* const* d_in, const int* in_sizes, int n_in,
                              void* d_out, int out_size, void* d_ws, size_t ws_size,
                              hipStream_t stream) {
  const float* x   = (const float*)d_in[0];
  const float* Wq  = (const float*)d_in[1];
  const float* Wk  = (const float*)d_in[2];
  const float* Wv  = (const float*)d_in[3];
  const float* Wo  = (const float*)d_in[4];
  const float* lq1 = (const float*)d_in[5];
  const float* lk1 = (const float*)d_in[6];
  const float* lq2 = (const float*)d_in[7];
  const float* lk2 = (const float*)d_in[8];
  float* out = (float*)d_out;

  char* ws = (char*)d_ws;
  size_t off = 0;
  auto alloc = [&](size_t bytes) -> char* {
    char* p = ws + off;
    off += (bytes + 255) & ~(size_t)255;
    return p;
  };
  bf16_t* xb  = (bf16_t*)alloc((size_t)4096 * 1024 * 2);
  bf16_t* Wqt = (bf16_t*)alloc((size_t)2048 * 1024 * 2);
  bf16_t* Wkt = (bf16_t*)alloc((size_t)2048 * 1024 * 2);
  bf16_t* Wvt = (bf16_t*)alloc((size_t)2048 * 1024 * 2);
  bf16_t* Wot = (bf16_t*)alloc((size_t)1024 * 1024 * 2);
  bf16_t* Qb  = (bf16_t*)alloc((size_t)4096 * 2048 * 2);
  bf16_t* Kb  = (bf16_t*)alloc((size_t)4096 * 2048 * 2);
  bf16_t* Vtg = (bf16_t*)alloc((size_t)4096 * 2048 * 2);
  bf16_t* Ob  = (bf16_t*)alloc((size_t)4096 * 1024 * 2);

  const float QSCALE = 0.125f * 1.44269504088896340736f;  // fold into Wq

  cvt_x_kernel<<<4096, 256, 0, stream>>>(x, xb);
  transpose_cvt_all<<<dim3(64, 32, 4), dim3(32, 8), 0, stream>>>(
      Wq, Wk, Wv, Wo, Wqt, Wkt, Wvt, Wot, QSCALE);
  gemm_qkv<<<dim3(16, 32, 3), 256, 0, stream>>>(xb, Wqt, Wkt, Wvt, Qb, Kb, Vtg);
  attn_kernel<<<256, 512, 0, stream>>>(Qb, Kb, Vtg, Ob, lq1, lk1, lq2, lk2);
  gemm_out<<<dim3(8, 32), 256, 0, stream>>>(Ob, Wot, out);
}

// Round 13
// 186.014 us; speedup vs baseline: 1.1661x; 1.0220x over previous
//
#include <hip/hip_runtime.h>
#include <hip/hip_bf16.h>

typedef __bf16 bf16_t;
typedef bf16_t bf16x8 __attribute__((ext_vector_type(8)));
typedef float f32x4 __attribute__((ext_vector_type(4)));
typedef float f32x16 __attribute__((ext_vector_type(16)));

static __device__ __forceinline__ f32x4 mfma16(bf16x8 a, bf16x8 b, f32x4 c) {
  return __builtin_amdgcn_mfma_f32_16x16x32_bf16(a, b, c, 0, 0, 0);
}
static __device__ __forceinline__ f32x16 mfma32(bf16x8 a, bf16x8 b, f32x16 c) {
  return __builtin_amdgcn_mfma_f32_32x32x16_bf16(a, b, c, 0, 0, 0);
}

static __device__ __forceinline__ void gload_lds16(const bf16_t* g, bf16_t* l) {
  __builtin_amdgcn_global_load_lds(
      (const __attribute__((address_space(1))) void*)g,
      (__attribute__((address_space(3))) void*)l, 16, 0, 0);
}

static __device__ __forceinline__ unsigned pkbf(float a, float b) {
  union { bf16_t h[2]; unsigned u; } p;
  p.h[0] = (bf16_t)a; p.h[1] = (bf16_t)b;
  return p.u;
}
static __device__ __forceinline__ void pl32swap(unsigned& a, unsigned& b) {
  asm volatile("v_permlane32_swap_b32 %0, %1" : "+v"(a), "+v"(b));
}

// ---------------------------------------------------------------- prep kernel
// z 0-3: weight transposes W [1024][N] fp32 -> Wt [N][1024] bf16 (z0 scaled).
// z 4: x fp32 -> bf16 conversion (grid-stride over 2048 linear blocks).

__global__ __launch_bounds__(256) void prep_all(
    const float* __restrict__ x, bf16_t* __restrict__ xb,
    const float* __restrict__ Wq, const float* __restrict__ Wk,
    const float* __restrict__ Wv, const float* __restrict__ Wo,
    bf16_t* __restrict__ Wqt, bf16_t* __restrict__ Wkt,
    bf16_t* __restrict__ Wvt, bf16_t* __restrict__ Wot, float qscale) {
  __shared__ float tile[32][33];
  const int z = blockIdx.z;
  const int tid = threadIdx.y * 32 + threadIdx.x;
  if (z == 4) {   // cvt_x: 2048 blocks x 2048 floats
    const int id = blockIdx.y * gridDim.x + blockIdx.x;   // 0..2047
    size_t base = (size_t)id * 2048 + tid * 4;
    #pragma unroll
    for (int pass = 0; pass < 2; ++pass) {
      float4 v = *reinterpret_cast<const float4*>(x + base + pass * 1024);
      union { bf16_t h[4]; uint2 u; } pk;
      pk.h[0] = (bf16_t)v.x; pk.h[1] = (bf16_t)v.y;
      pk.h[2] = (bf16_t)v.z; pk.h[3] = (bf16_t)v.w;
      *reinterpret_cast<uint2*>(xb + base + pass * 1024) = pk.u;
    }
    return;
  }
  const float* W; bf16_t* Wt; int N; float scale = 1.0f;
  if (z == 0)      { W = Wq; Wt = Wqt; N = 2048; scale = qscale; }
  else if (z == 1) { W = Wk; Wt = Wkt; N = 2048; }
  else if (z == 2) { W = Wv; Wt = Wvt; N = 2048; }
  else             { W = Wo; Wt = Wot; N = 1024; if (blockIdx.x >= 32) return; }
  const int K = 1024;
  int n0 = blockIdx.x * 32, k0 = blockIdx.y * 32;
  int xx = threadIdx.x, y = threadIdx.y;  // 32 x 8
  #pragma unroll
  for (int i = 0; i < 32; i += 8)
    tile[y + i][xx] = W[(size_t)(k0 + y + i) * N + n0 + xx];
  __syncthreads();
  #pragma unroll
  for (int i = 0; i < 32; i += 8)
    Wt[(size_t)(n0 + y + i) * K + k0 + xx] = (bf16_t)(tile[xx][y + i] * scale);
}

// ---------------------------------------------------------------- GEMM (A[M][K] x Bt[N][K]^T)
// BK=64 as TWO verbatim 32-K slabs per barrier pair: staging geometry, LDS
// layout, and fragment reads are byte-identical to the verified BK=32 body,
// duplicated at k0 and k0+32 into separate slab regions. Halves barrier/drain
// events per FLOP; LDS 2x16KB->2x32KB (96KB at 3 blocks/CU, occupancy kept).

template <typename OutT>
static __device__ __forceinline__ void gemm_bt_body(const bf16_t* __restrict__ A,
                                                    const bf16_t* __restrict__ Bt,
                                                    OutT* __restrict__ C,
                                                    int M, int N, int K,
                                                    bool vtrans) {
  __shared__ bf16_t As[2][128 * 32];
  __shared__ bf16_t Bs[2][128 * 32];
  const int tid = threadIdx.x;
  const int w = tid >> 6, lane = tid & 63;
  const int g = lane >> 4, l15 = lane & 15;
  const int wm = w >> 1, wn = w & 1;

  // T1: XCD-contiguous block swizzle (n = gridDim.x*gridDim.y divisible by 8)
  const int nbx = gridDim.x;
  const int idx = blockIdx.y * nbx + blockIdx.x;
  const int qq = (nbx * gridDim.y) >> 3;
  const int sidx = (idx & 7) * qq + (idx >> 3);
  const int rowBase = (sidx / nbx) * 128, colBase = (sidx % nbx) * 128;

  const int c0 = 2 * w, c1 = 2 * w + 1;
  const int srow0 = 16 * c0 + (lane >> 2);
  const int srow1 = 16 * c1 + (lane >> 2);
  const int scol = (lane & 3) * 8;

  f32x4 acc[4][4] = {};

  for (int k0 = 0; k0 < K; k0 += 64) {
    __syncthreads();
    #pragma unroll
    for (int sl = 0; sl < 2; ++sl) {
      const int kk = k0 + sl * 32;
      gload_lds16(A + (size_t)(rowBase + srow0) * K + kk + scol, &As[sl][c0 * 512]);
      gload_lds16(A + (size_t)(rowBase + srow1) * K + kk + scol, &As[sl][c1 * 512]);
      gload_lds16(Bt + (size_t)(colBase + srow0) * K + kk + scol, &Bs[sl][c0 * 512]);
      gload_lds16(Bt + (size_t)(colBase + srow1) * K + kk + scol, &Bs[sl][c1 * 512]);
    }
    __syncthreads();

    #pragma unroll
    for (int sl = 0; sl < 2; ++sl) {
      bf16x8 bfr[4];
      #pragma unroll
      for (int j = 0; j < 4; ++j)
        bfr[j] = *reinterpret_cast<const bf16x8*>(&Bs[sl][(wn * 64 + j * 16 + l15) * 32 + g * 8]);
      #pragma unroll
      for (int i = 0; i < 4; ++i) {
        bf16x8 afr = *reinterpret_cast<const bf16x8*>(&As[sl][(wm * 64 + i * 16 + l15) * 32 + g * 8]);
        #pragma unroll
        for (int j = 0; j < 4; ++j)
          acc[i][j] = mfma16(afr, bfr[j], acc[i][j]);
      }
    }
  }

  if (vtrans) {
    #pragma unroll
    for (int i = 0; i < 4; ++i) {
      #pragma unroll
      for (int j = 0; j < 4; ++j) {
        int row = rowBase + wm * 64 + i * 16 + 4 * g;  // global s in [0,4096)
        int col = colBase + wn * 64 + j * 16 + l15;    // [0,2048)
        int bb = row >> 11, s = row & 2047;
        union { bf16_t h[4]; uint2 u; } pk;
        #pragma unroll
        for (int r = 0; r < 4; ++r) pk.h[r] = (bf16_t)acc[i][j][r];
        *reinterpret_cast<uint2*>(
            (bf16_t*)C + ((size_t)bb * 2048 + col) * 2048 + s) = pk.u;
      }
    }
  } else {
    #pragma unroll
    for (int i = 0; i < 4; ++i) {
      #pragma unroll
      for (int j = 0; j < 4; ++j) {
        int row = rowBase + wm * 64 + i * 16 + 4 * g;
        int col = colBase + wn * 64 + j * 16 + l15;
        #pragma unroll
        for (int r = 0; r < 4; ++r)
          C[(size_t)(row + r) * N + col] = (OutT)acc[i][j][r];
      }
    }
  }
}

__global__ __launch_bounds__(256) void gemm_qkv(const bf16_t* __restrict__ xb,
                                                const bf16_t* __restrict__ Wqt,
                                                const bf16_t* __restrict__ Wkt,
                                                const bf16_t* __restrict__ Wvt,
                                                bf16_t* __restrict__ Q,
                                                bf16_t* __restrict__ K,
                                                bf16_t* __restrict__ Vtg) {
  const bf16_t* Bt = (blockIdx.z == 0) ? Wqt : (blockIdx.z == 1) ? Wkt : Wvt;
  bf16_t* C = (blockIdx.z == 0) ? Q : (blockIdx.z == 1) ? K : Vtg;
  gemm_bt_body<bf16_t>(xb, Bt, C, 4096, 2048, 1024, blockIdx.z == 2);
}

__global__ __launch_bounds__(256) void gemm_out(const bf16_t* __restrict__ Ob,
                                                const bf16_t* __restrict__ Wot,
                                                float* __restrict__ out) {
  gemm_bt_body<float>(Ob, Wot, out, 4096, 1024, 1024, false);
}

// ---------------------------------------------------------------- attention
// R12 kernel VERBATIM (verified, 97.0us): 256 blocks x 512 thr, 1 block/CU,
// KVBLK=128, pair {p,15-p} = 17 iters; Q pre-scaled by 0.125*log2e in Wqt;
// rowsum via ones-B MFMA; finalize scratch stride 33 (conflict-free);
// in-kernel lambda; T5 setprio.
// LDS (64KB): K [comp*128+key][128B swz] | V +32KB [comp*64+d][256B swz].

__global__ __launch_bounds__(512, 1)
void attn_kernel(const bf16_t* __restrict__ Qg, const bf16_t* __restrict__ Kg,
                 const bf16_t* __restrict__ Vtg, bf16_t* __restrict__ Og,
                 const float* __restrict__ lq1, const float* __restrict__ lk1,
                 const float* __restrict__ lq2, const float* __restrict__ lk2) {
  __shared__ __align__(16) char ldsbuf[65536];

  const int tid = threadIdx.x;
  const int w = tid >> 6, lane = tid & 63;
  const int l31 = lane & 31, hi = lane >> 5;
  const int sw7 = l31 & 7;
  const int rowg = w & 3, keyh = w >> 2;
  const int bx = blockIdx.x;
  const int p = bx >> 5;            // pair 0..7 -> tiles {p, 15-p}
  const int bh = bx & 31;
  const int b = bh >> 4, h = bh & 15;
  const int rowB = b * 2048;

  // ---- lambda, computed per-wave
  float lam;
  {
    float a = lq1[lane] * lk1[lane];
    float c = lq2[lane] * lk2[lane];
    #pragma unroll
    for (int msk = 32; msk; msk >>= 1) {
      a += __shfl_xor(a, msk);
      c += __shfl_xor(c, msk);
    }
    lam = __expf(a) - __expf(c) + 0.8f;
  }

  const bf16_t one = (bf16_t)1.0f;
  const bf16x8 ones = {one, one, one, one, one, one, one, one};

  // ---- staging constants (verbatim R3/R4/R7 lineage)
  const int lk8 = lane >> 3;               // K: row-within-8
  const int sc8 = (lane & 7) ^ lk8;        // K: pre-swizzled source chunk
  const int lk4 = lane >> 4;               // V: row-within-4
  const int wv = (w - 4) & 3;
  const size_t kOff = (size_t)(rowB + ((w & 1) << 6) + lk8) * 2048 +
                      (w >> 1) * 1024 + h * 64 + sc8 * 8;           // w<4
  const size_t vOff = ((size_t)b * 2048 + (wv >> 1) * 1024 + h * 64 +
                       ((wv & 1) << 5) + lk4) * 2048;               // w>=4

  auto stage = [&](char* bufb, int j0) {
    if (w < 4) {
      const bf16_t* src = Kg + kOff + (size_t)j0 * 2048;
      char* dst = bufb + w * 8192;
      #pragma unroll
      for (int t = 0; t < 8; ++t)
        gload_lds16(src + (size_t)t * (8 * 2048), (bf16_t*)(dst + t * 1024));
    } else {
      const bf16_t* src = Vtg + vOff + j0;
      char* dst = bufb + 32768 + wv * 8192;
      #pragma unroll
      for (int t = 0; t < 8; ++t) {
        int sc16 = (lane & 15) ^ (((t & 1) << 2) + lk4);
        gload_lds16(src + (size_t)t * (4 * 2048) + sc16 * 8,
                    (bf16_t*)(dst + t * 1024));
      }
    }
  };

  f32x16 o[2][2];
  f32x16 lsum[2];
  bf16x8 qf[2][4];

  // ---- phase-end: combine key-half partials via freed LDS buffer
  // (stride 33 floats, conflict-free); normalize, store.
  auto finalize = [&](int q0, char* scratch) {
    float* sf = (float*)scratch;
    #pragma unroll
    for (int rd = 0; rd < 4; ++rd) {
      const int comp = rd >> 1, db = rd & 1;
      __syncthreads();
      if (w >= 4) {
        float* bp = sf + (size_t)((w - 4) * 64 + lane) * 33;
        #pragma unroll
        for (int e = 0; e < 16; ++e) bp[e] = o[comp][db][e];
        if (db == 0) {
          #pragma unroll
          for (int e = 0; e < 16; ++e) bp[16 + e] = lsum[comp][e];
        }
      }
      __syncthreads();
      if (w < 4) {
        const float* bp = sf + (size_t)(w * 64 + lane) * 33;
        #pragma unroll
        for (int e = 0; e < 16; ++e) o[comp][db][e] += bp[e];
        if (db == 0) {
          #pragma unroll
          for (int e = 0; e < 16; ++e) lsum[comp][e] += bp[16 + e];
        }
      }
    }
    __syncthreads();  // scratch reads done
    if (w < 4) {
      #pragma unroll
      for (int e = 0; e < 16; ++e) {
        int ql = (e & 3) + 8 * (e >> 2) + 4 * hi;
        float i1 = 1.f / lsum[0][e];
        float i2 = lam / lsum[1][e];
        int row = rowB + q0 + w * 32 + ql;
        size_t rb = (size_t)row * 1024 + h * 64 + l31;
        Og[rb]      = (bf16_t)((o[0][0][e] * i1 - o[1][0][e] * i2) * 0.2f);
        Og[rb + 32] = (bf16_t)((o[0][1][e] * i1 - o[1][1][e] * i2) * 0.2f);
      }
    }
  };

  #pragma unroll 1
  for (int i = 0; i <= 16; ++i) {
    const int q0 = (i > p ? 15 - p : p) << 7;
    const int j0 = (i > p ? i - p - 1 : i) << 7;

    __syncthreads();          // everyone done with buffer (compute/finalize)
    stage(ldsbuf, j0);        // async global->LDS

    if (i == 0 || i == p + 1) {  // phase start under staging latency
      #pragma unroll
      for (int comp = 0; comp < 2; ++comp)
        #pragma unroll
        for (int s = 0; s < 4; ++s)
          qf[comp][s] = *reinterpret_cast<const bf16x8*>(
              Qg + (size_t)(rowB + q0 + rowg * 32 + l31) * 2048 + comp * 1024 +
              h * 64 + s * 16 + hi * 8);
      #pragma unroll
      for (int comp = 0; comp < 2; ++comp) {
        o[comp][0] = (f32x16)0.f;
        o[comp][1] = (f32x16)0.f;
        lsum[comp] = (f32x16)0.f;
      }
    }

    __syncthreads();          // staged data visible (drains vmcnt)

    const char* bufb = (const char*)ldsbuf;
    const int rowbase = q0 + rowg * 32;
    const int qg = rowbase + l31;
    const bool active = (j0 + keyh * 64) <= (rowbase + 31);
    if (active) {
      const bool maskt = (j0 + keyh * 64 + 63) > rowbase;
      #pragma unroll
      for (int comp = 0; comp < 2; ++comp) {
        const char* Kb = bufb + comp * 16384 + keyh * 64 * 128;
        const char* Vb = bufb + 32768 + comp * 16384;
        // ---- per 32-key half: S' = K Q^T -> P -> pa -> PV + lsum
        #pragma unroll
        for (int kb = 0; kb < 2; ++kb) {
          f32x16 sA = {};
          __builtin_amdgcn_s_setprio(1);
          #pragma unroll
          for (int s = 0; s < 4; ++s) {
            int xo = ((2 * s + hi) ^ sw7) << 4;
            bf16x8 kf = *reinterpret_cast<const bf16x8*>(
                Kb + (kb * 32 + l31) * 128 + xo);
            sA = mfma32(kf, qf[comp][s], sA);
          }
          __builtin_amdgcn_s_setprio(0);
          float pv[16];
          #pragma unroll
          for (int e = 0; e < 16; ++e) {
            float v = __builtin_exp2f(sA[e]);   // Q pre-scaled by 0.125*log2e
            if (maskt) {
              int krow = (e & 3) + 8 * (e >> 2) + 4 * hi;
              if (j0 + keyh * 64 + kb * 32 + krow > qg) v = 0.f;
            }
            pv[e] = v;
          }
          bf16x8 pa[2];
          #pragma unroll
          for (int sp = 0; sp < 2; ++sp) {
            unsigned u0 = pkbf(pv[8 * sp + 0], pv[8 * sp + 1]);
            unsigned u1 = pkbf(pv[8 * sp + 2], pv[8 * sp + 3]);
            unsigned v0 = pkbf(pv[8 * sp + 4], pv[8 * sp + 5]);
            unsigned v1 = pkbf(pv[8 * sp + 6], pv[8 * sp + 7]);
            pl32swap(u0, v0);
            pl32swap(u1, v1);
            union { uint4 u; bf16x8 f; } cvt;
            cvt.u = make_uint4(u0, u1, v0, v1);
            pa[sp] = cvt.f;
          }
          __builtin_amdgcn_s_setprio(1);
          #pragma unroll
          for (int sp = 0; sp < 2; ++sp) {
            int s = kb * 2 + sp;
            int sl = ((keyh * 8) | ((2 * s + hi) ^ sw7)) << 4;
            bf16x8 vf0 = *reinterpret_cast<const bf16x8*>(Vb + l31 * 256 + sl);
            bf16x8 vf1 = *reinterpret_cast<const bf16x8*>(Vb + (32 + l31) * 256 + sl);
            o[comp][0] = mfma32(pa[sp], vf0, o[comp][0]);
            o[comp][1] = mfma32(pa[sp], vf1, o[comp][1]);
            lsum[comp] = mfma32(pa[sp], ones, lsum[comp]);
          }
          __builtin_amdgcn_s_setprio(0);
        }
      }
    }

    if (i == p || i == 16) finalize(q0, ldsbuf);
  }
}

// ---------------------------------------------------------------- launch

extern "C" void kernel_launch(void* const* d_in, const int* in_sizes, int n_in,
                              void* d_out, int out_size, void* d_ws, size_t ws_size,
                              hipStream_t stream) {
  const float* x   = (const float*)d_in[0];
  const float* Wq  = (const float*)d_in[1];
  const float* Wk  = (const float*)d_in[2];
  const float* Wv  = (const float*)d_in[3];
  const float* Wo  = (const float*)d_in[4];
  const float* lq1 = (const float*)d_in[5];
  const float* lk1 = (const float*)d_in[6];
  const float* lq2 = (const float*)d_in[7];
  const float* lk2 = (const float*)d_in[8];
  float* out = (float*)d_out;

  char* ws = (char*)d_ws;
  size_t off = 0;
  auto alloc = [&](size_t bytes) -> char* {
    char* p = ws + off;
    off += (bytes + 255) & ~(size_t)255;
    return p;
  };
  bf16_t* xb  = (bf16_t*)alloc((size_t)4096 * 1024 * 2);
  bf16_t* Wqt = (bf16_t*)alloc((size_t)2048 * 1024 * 2);
  bf16_t* Wkt = (bf16_t*)alloc((size_t)2048 * 1024 * 2);
  bf16_t* Wvt = (bf16_t*)alloc((size_t)2048 * 1024 * 2);
  bf16_t* Wot = (bf16_t*)alloc((size_t)1024 * 1024 * 2);
  bf16_t* Qb  = (bf16_t*)alloc((size_t)4096 * 2048 * 2);
  bf16_t* Kb  = (bf16_t*)alloc((size_t)4096 * 2048 * 2);
  bf16_t* Vtg = (bf16_t*)alloc((size_t)4096 * 2048 * 2);
  bf16_t* Ob  = (bf16_t*)alloc((size_t)4096 * 1024 * 2);

  const float QSCALE = 0.125f * 1.44269504088896340736f;  // fold into Wq

  prep_all<<<dim3(64, 32, 5), dim3(32, 8), 0, stream>>>(
      x, xb, Wq, Wk, Wv, Wo, Wqt, Wkt, Wvt, Wot, QSCALE);
  gemm_qkv<<<dim3(16, 32, 3), 256, 0, stream>>>(xb, Wqt, Wkt, Wvt, Qb, Kb, Vtg);
  attn_kernel<<<256, 512, 0, stream>>>(Qb, Kb, Vtg, Ob, lq1, lk1, lq2, lk2);
  gemm_out<<<dim3(8, 32), 256, 0, stream>>>(Ob, Wot, out);
}

// Round 14
// 185.660 us; speedup vs baseline: 1.1684x; 1.0019x over previous
//
#include <hip/hip_runtime.h>
#include <hip/hip_bf16.h>

typedef __bf16 bf16_t;
typedef bf16_t bf16x8 __attribute__((ext_vector_type(8)));
typedef float f32x4 __attribute__((ext_vector_type(4)));
typedef float f32x16 __attribute__((ext_vector_type(16)));

static __device__ __forceinline__ f32x4 mfma16(bf16x8 a, bf16x8 b, f32x4 c) {
  return __builtin_amdgcn_mfma_f32_16x16x32_bf16(a, b, c, 0, 0, 0);
}
static __device__ __forceinline__ f32x16 mfma32(bf16x8 a, bf16x8 b, f32x16 c) {
  return __builtin_amdgcn_mfma_f32_32x32x16_bf16(a, b, c, 0, 0, 0);
}

static __device__ __forceinline__ void gload_lds16(const bf16_t* g, bf16_t* l) {
  __builtin_amdgcn_global_load_lds(
      (const __attribute__((address_space(1))) void*)g,
      (__attribute__((address_space(3))) void*)l, 16, 0, 0);
}

static __device__ __forceinline__ unsigned pkbf(float a, float b) {
  union { bf16_t h[2]; unsigned u; } p;
  p.h[0] = (bf16_t)a; p.h[1] = (bf16_t)b;
  return p.u;
}
static __device__ __forceinline__ void pl32swap(unsigned& a, unsigned& b) {
  asm volatile("v_permlane32_swap_b32 %0, %1" : "+v"(a), "+v"(b));
}

// ---------------------------------------------------------------- prep kernel
// z 0-3: weight transposes W [1024][N] fp32 -> Wt [N][1024] bf16 (z0 scaled).
// z 4: x fp32 -> bf16 conversion (grid-stride over 2048 linear blocks).

__global__ __launch_bounds__(256) void prep_all(
    const float* __restrict__ x, bf16_t* __restrict__ xb,
    const float* __restrict__ Wq, const float* __restrict__ Wk,
    const float* __restrict__ Wv, const float* __restrict__ Wo,
    bf16_t* __restrict__ Wqt, bf16_t* __restrict__ Wkt,
    bf16_t* __restrict__ Wvt, bf16_t* __restrict__ Wot, float qscale) {
  __shared__ float tile[32][33];
  const int z = blockIdx.z;
  const int tid = threadIdx.y * 32 + threadIdx.x;
  if (z == 4) {   // cvt_x: 2048 blocks x 2048 floats
    const int id = blockIdx.y * gridDim.x + blockIdx.x;   // 0..2047
    size_t base = (size_t)id * 2048 + tid * 4;
    #pragma unroll
    for (int pass = 0; pass < 2; ++pass) {
      float4 v = *reinterpret_cast<const float4*>(x + base + pass * 1024);
      union { bf16_t h[4]; uint2 u; } pk;
      pk.h[0] = (bf16_t)v.x; pk.h[1] = (bf16_t)v.y;
      pk.h[2] = (bf16_t)v.z; pk.h[3] = (bf16_t)v.w;
      *reinterpret_cast<uint2*>(xb + base + pass * 1024) = pk.u;
    }
    return;
  }
  const float* W; bf16_t* Wt; int N; float scale = 1.0f;
  if (z == 0)      { W = Wq; Wt = Wqt; N = 2048; scale = qscale; }
  else if (z == 1) { W = Wk; Wt = Wkt; N = 2048; }
  else if (z == 2) { W = Wv; Wt = Wvt; N = 2048; }
  else             { W = Wo; Wt = Wot; N = 1024; if (blockIdx.x >= 32) return; }
  const int K = 1024;
  int n0 = blockIdx.x * 32, k0 = blockIdx.y * 32;
  int xx = threadIdx.x, y = threadIdx.y;  // 32 x 8
  #pragma unroll
  for (int i = 0; i < 32; i += 8)
    tile[y + i][xx] = W[(size_t)(k0 + y + i) * N + n0 + xx];
  __syncthreads();
  #pragma unroll
  for (int i = 0; i < 32; i += 8)
    Wt[(size_t)(n0 + y + i) * K + k0 + xx] = (bf16_t)(tile[xx][y + i] * scale);
}

// ---------------------------------------------------------------- GEMM (A[M][K] x Bt[N][K]^T)
// BK=64 as TWO verbatim 32-K slabs per barrier pair (R13, verified).

template <typename OutT>
static __device__ __forceinline__ void gemm_bt_body(const bf16_t* __restrict__ A,
                                                    const bf16_t* __restrict__ Bt,
                                                    OutT* __restrict__ C,
                                                    int M, int N, int K,
                                                    bool vtrans) {
  __shared__ bf16_t As[2][128 * 32];
  __shared__ bf16_t Bs[2][128 * 32];
  const int tid = threadIdx.x;
  const int w = tid >> 6, lane = tid & 63;
  const int g = lane >> 4, l15 = lane & 15;
  const int wm = w >> 1, wn = w & 1;

  // T1: XCD-contiguous block swizzle (n = gridDim.x*gridDim.y divisible by 8)
  const int nbx = gridDim.x;
  const int idx = blockIdx.y * nbx + blockIdx.x;
  const int qq = (nbx * gridDim.y) >> 3;
  const int sidx = (idx & 7) * qq + (idx >> 3);
  const int rowBase = (sidx / nbx) * 128, colBase = (sidx % nbx) * 128;

  const int c0 = 2 * w, c1 = 2 * w + 1;
  const int srow0 = 16 * c0 + (lane >> 2);
  const int srow1 = 16 * c1 + (lane >> 2);
  const int scol = (lane & 3) * 8;

  f32x4 acc[4][4] = {};

  for (int k0 = 0; k0 < K; k0 += 64) {
    __syncthreads();
    #pragma unroll
    for (int sl = 0; sl < 2; ++sl) {
      const int kk = k0 + sl * 32;
      gload_lds16(A + (size_t)(rowBase + srow0) * K + kk + scol, &As[sl][c0 * 512]);
      gload_lds16(A + (size_t)(rowBase + srow1) * K + kk + scol, &As[sl][c1 * 512]);
      gload_lds16(Bt + (size_t)(colBase + srow0) * K + kk + scol, &Bs[sl][c0 * 512]);
      gload_lds16(Bt + (size_t)(colBase + srow1) * K + kk + scol, &Bs[sl][c1 * 512]);
    }
    __syncthreads();

    #pragma unroll
    for (int sl = 0; sl < 2; ++sl) {
      bf16x8 bfr[4];
      #pragma unroll
      for (int j = 0; j < 4; ++j)
        bfr[j] = *reinterpret_cast<const bf16x8*>(&Bs[sl][(wn * 64 + j * 16 + l15) * 32 + g * 8]);
      #pragma unroll
      for (int i = 0; i < 4; ++i) {
        bf16x8 afr = *reinterpret_cast<const bf16x8*>(&As[sl][(wm * 64 + i * 16 + l15) * 32 + g * 8]);
        #pragma unroll
        for (int j = 0; j < 4; ++j)
          acc[i][j] = mfma16(afr, bfr[j], acc[i][j]);
      }
    }
  }

  if (vtrans) {
    #pragma unroll
    for (int i = 0; i < 4; ++i) {
      #pragma unroll
      for (int j = 0; j < 4; ++j) {
        int row = rowBase + wm * 64 + i * 16 + 4 * g;  // global s in [0,4096)
        int col = colBase + wn * 64 + j * 16 + l15;    // [0,2048)
        int bb = row >> 11, s = row & 2047;
        union { bf16_t h[4]; uint2 u; } pk;
        #pragma unroll
        for (int r = 0; r < 4; ++r) pk.h[r] = (bf16_t)acc[i][j][r];
        *reinterpret_cast<uint2*>(
            (bf16_t*)C + ((size_t)bb * 2048 + col) * 2048 + s) = pk.u;
      }
    }
  } else {
    #pragma unroll
    for (int i = 0; i < 4; ++i) {
      #pragma unroll
      for (int j = 0; j < 4; ++j) {
        int row = rowBase + wm * 64 + i * 16 + 4 * g;
        int col = colBase + wn * 64 + j * 16 + l15;
        #pragma unroll
        for (int r = 0; r < 4; ++r)
          C[(size_t)(row + r) * N + col] = (OutT)acc[i][j][r];
      }
    }
  }
}

__global__ __launch_bounds__(256) void gemm_qkv(const bf16_t* __restrict__ xb,
                                                const bf16_t* __restrict__ Wqt,
                                                const bf16_t* __restrict__ Wkt,
                                                const bf16_t* __restrict__ Wvt,
                                                bf16_t* __restrict__ Q,
                                                bf16_t* __restrict__ K,
                                                bf16_t* __restrict__ Vtg) {
  const bf16_t* Bt = (blockIdx.z == 0) ? Wqt : (blockIdx.z == 1) ? Wkt : Wvt;
  bf16_t* C = (blockIdx.z == 0) ? Q : (blockIdx.z == 1) ? K : Vtg;
  gemm_bt_body<bf16_t>(xb, Bt, C, 4096, 2048, 1024, blockIdx.z == 2);
}

__global__ __launch_bounds__(256) void gemm_out(const bf16_t* __restrict__ Ob,
                                                const bf16_t* __restrict__ Wot,
                                                float* __restrict__ out) {
  gemm_bt_body<float>(Ob, Wot, out, 4096, 1024, 1024, false);
}

// ---------------------------------------------------------------- attention
// R12/R13 kernel with KVBLK=256 as TWO verbatim 128-key sub-tiles per barrier
// pair (same slab trick as the R13 GEMM): stage() called at jj0 and jj0+128
// into two 64KB regions, ONE drain+barrier, then the verified compute body per
// sub-tile. Iterations 17 -> 9 (uniform: nd1=(p>>1)+1 for tile p, 9-nd1 for
// tile 15-p; exactly one all-masked half-tile of waste, skipped via `active`).
// LDS 128KB, 1 block/CU (unchanged). All index formulas are the verified
// lineage with j0 -> jj substitution.

__global__ __launch_bounds__(512, 1)
void attn_kernel(const bf16_t* __restrict__ Qg, const bf16_t* __restrict__ Kg,
                 const bf16_t* __restrict__ Vtg, bf16_t* __restrict__ Og,
                 const float* __restrict__ lq1, const float* __restrict__ lk1,
                 const float* __restrict__ lq2, const float* __restrict__ lk2) {
  __shared__ __align__(16) char ldsbuf[131072];

  const int tid = threadIdx.x;
  const int w = tid >> 6, lane = tid & 63;
  const int l31 = lane & 31, hi = lane >> 5;
  const int sw7 = l31 & 7;
  const int rowg = w & 3, keyh = w >> 2;
  const int bx = blockIdx.x;
  const int p = bx >> 5;            // pair 0..7 -> tiles {p, 15-p}
  const int bh = bx & 31;
  const int b = bh >> 4, h = bh & 15;
  const int rowB = b * 2048;
  const int nd1 = (p >> 1) + 1;     // double-iters for tile p (9-nd1 for 15-p)

  // ---- lambda, computed per-wave
  float lam;
  {
    float a = lq1[lane] * lk1[lane];
    float c = lq2[lane] * lk2[lane];
    #pragma unroll
    for (int msk = 32; msk; msk >>= 1) {
      a += __shfl_xor(a, msk);
      c += __shfl_xor(c, msk);
    }
    lam = __expf(a) - __expf(c) + 0.8f;
  }

  const bf16_t one = (bf16_t)1.0f;
  const bf16x8 ones = {one, one, one, one, one, one, one, one};

  // ---- staging constants (verbatim R3/R4/R7 lineage)
  const int lk8 = lane >> 3;               // K: row-within-8
  const int sc8 = (lane & 7) ^ lk8;        // K: pre-swizzled source chunk
  const int lk4 = lane >> 4;               // V: row-within-4
  const int wv = (w - 4) & 3;
  const size_t kOff = (size_t)(rowB + ((w & 1) << 6) + lk8) * 2048 +
                      (w >> 1) * 1024 + h * 64 + sc8 * 8;           // w<4
  const size_t vOff = ((size_t)b * 2048 + (wv >> 1) * 1024 + h * 64 +
                       ((wv & 1) << 5) + lk4) * 2048;               // w>=4

  auto stage = [&](char* bufb, int j0) {
    if (w < 4) {
      const bf16_t* src = Kg + kOff + (size_t)j0 * 2048;
      char* dst = bufb + w * 8192;
      #pragma unroll
      for (int t = 0; t < 8; ++t)
        gload_lds16(src + (size_t)t * (8 * 2048), (bf16_t*)(dst + t * 1024));
    } else {
      const bf16_t* src = Vtg + vOff + j0;
      char* dst = bufb + 32768 + wv * 8192;
      #pragma unroll
      for (int t = 0; t < 8; ++t) {
        int sc16 = (lane & 15) ^ (((t & 1) << 2) + lk4);
        gload_lds16(src + (size_t)t * (4 * 2048) + sc16 * 8,
                    (bf16_t*)(dst + t * 1024));
      }
    }
  };

  f32x16 o[2][2];
  f32x16 lsum[2];
  bf16x8 qf[2][4];

  // ---- phase-end: combine key-half partials via freed LDS buffer
  // (stride 33 floats, conflict-free); normalize, store.
  auto finalize = [&](int q0, char* scratch) {
    float* sf = (float*)scratch;
    #pragma unroll
    for (int rd = 0; rd < 4; ++rd) {
      const int comp = rd >> 1, db = rd & 1;
      __syncthreads();
      if (w >= 4) {
        float* bp = sf + (size_t)((w - 4) * 64 + lane) * 33;
        #pragma unroll
        for (int e = 0; e < 16; ++e) bp[e] = o[comp][db][e];
        if (db == 0) {
          #pragma unroll
          for (int e = 0; e < 16; ++e) bp[16 + e] = lsum[comp][e];
        }
      }
      __syncthreads();
      if (w < 4) {
        const float* bp = sf + (size_t)(w * 64 + lane) * 33;
        #pragma unroll
        for (int e = 0; e < 16; ++e) o[comp][db][e] += bp[e];
        if (db == 0) {
          #pragma unroll
          for (int e = 0; e < 16; ++e) lsum[comp][e] += bp[16 + e];
        }
      }
    }
    __syncthreads();  // scratch reads done
    if (w < 4) {
      #pragma unroll
      for (int e = 0; e < 16; ++e) {
        int ql = (e & 3) + 8 * (e >> 2) + 4 * hi;
        float i1 = 1.f / lsum[0][e];
        float i2 = lam / lsum[1][e];
        int row = rowB + q0 + w * 32 + ql;
        size_t rb = (size_t)row * 1024 + h * 64 + l31;
        Og[rb]      = (bf16_t)((o[0][0][e] * i1 - o[1][0][e] * i2) * 0.2f);
        Og[rb + 32] = (bf16_t)((o[0][1][e] * i1 - o[1][1][e] * i2) * 0.2f);
      }
    }
  };

  #pragma unroll 1
  for (int i = 0; i < 9; ++i) {
    const int q0 = (i < nd1 ? p : 15 - p) << 7;
    const int jj0 = (i < nd1 ? i : i - nd1) << 8;   // 256-key double-tile base

    __syncthreads();               // everyone done with buffer (compute/finalize)
    stage(ldsbuf, jj0);            // sub-tile A: keys [jj0, jj0+128)
    stage(ldsbuf + 65536, jj0 + 128);  // sub-tile B: keys [jj0+128, jj0+256)

    if (i == 0 || i == nd1) {      // phase start under staging latency
      #pragma unroll
      for (int comp = 0; comp < 2; ++comp)
        #pragma unroll
        for (int s = 0; s < 4; ++s)
          qf[comp][s] = *reinterpret_cast<const bf16x8*>(
              Qg + (size_t)(rowB + q0 + rowg * 32 + l31) * 2048 + comp * 1024 +
              h * 64 + s * 16 + hi * 8);
      #pragma unroll
      for (int comp = 0; comp < 2; ++comp) {
        o[comp][0] = (f32x16)0.f;
        o[comp][1] = (f32x16)0.f;
        lsum[comp] = (f32x16)0.f;
      }
    }

    __syncthreads();               // staged data visible (drains vmcnt)

    const int rowbase = q0 + rowg * 32;
    const int qg = rowbase + l31;

    #pragma unroll 1
    for (int st = 0; st < 2; ++st) {
      const int j0 = jj0 + st * 128;
      const char* bufb = (const char*)ldsbuf + st * 65536;
      const bool active = (j0 + keyh * 64) <= (rowbase + 31);
      if (active) {
        const bool maskt = (j0 + keyh * 64 + 63) > rowbase;
        #pragma unroll
        for (int comp = 0; comp < 2; ++comp) {
          const char* Kb = bufb + comp * 16384 + keyh * 64 * 128;
          const char* Vb = bufb + 32768 + comp * 16384;
          // ---- per 32-key half: S' = K Q^T -> P -> pa -> PV + lsum
          #pragma unroll
          for (int kb = 0; kb < 2; ++kb) {
            f32x16 sA = {};
            __builtin_amdgcn_s_setprio(1);
            #pragma unroll
            for (int s = 0; s < 4; ++s) {
              int xo = ((2 * s + hi) ^ sw7) << 4;
              bf16x8 kf = *reinterpret_cast<const bf16x8*>(
                  Kb + (kb * 32 + l31) * 128 + xo);
              sA = mfma32(kf, qf[comp][s], sA);
            }
            __builtin_amdgcn_s_setprio(0);
            float pv[16];
            #pragma unroll
            for (int e = 0; e < 16; ++e) {
              float v = __builtin_exp2f(sA[e]);   // Q pre-scaled by 0.125*log2e
              if (maskt) {
                int krow = (e & 3) + 8 * (e >> 2) + 4 * hi;
                if (j0 + keyh * 64 + kb * 32 + krow > qg) v = 0.f;
              }
              pv[e] = v;
            }
            bf16x8 pa[2];
            #pragma unroll
            for (int sp = 0; sp < 2; ++sp) {
              unsigned u0 = pkbf(pv[8 * sp + 0], pv[8 * sp + 1]);
              unsigned u1 = pkbf(pv[8 * sp + 2], pv[8 * sp + 3]);
              unsigned v0 = pkbf(pv[8 * sp + 4], pv[8 * sp + 5]);
              unsigned v1 = pkbf(pv[8 * sp + 6], pv[8 * sp + 7]);
              pl32swap(u0, v0);
              pl32swap(u1, v1);
              union { uint4 u; bf16x8 f; } cvt;
              cvt.u = make_uint4(u0, u1, v0, v1);
              pa[sp] = cvt.f;
            }
            __builtin_amdgcn_s_setprio(1);
            #pragma unroll
            for (int sp = 0; sp < 2; ++sp) {
              int s = kb * 2 + sp;
              int sl = ((keyh * 8) | ((2 * s + hi) ^ sw7)) << 4;
              bf16x8 vf0 = *reinterpret_cast<const bf16x8*>(Vb + l31 * 256 + sl);
              bf16x8 vf1 = *reinterpret_cast<const bf16x8*>(Vb + (32 + l31) * 256 + sl);
              o[comp][0] = mfma32(pa[sp], vf0, o[comp][0]);
              o[comp][1] = mfma32(pa[sp], vf1, o[comp][1]);
              lsum[comp] = mfma32(pa[sp], ones, lsum[comp]);
            }
            __builtin_amdgcn_s_setprio(0);
          }
        }
      }
    }

    if (i == nd1 - 1 || i == 8) finalize(q0, ldsbuf);
  }
}

// ---------------------------------------------------------------- launch

extern "C" void kernel_launch(void* const* d_in, const int* in_sizes, int n_in,
                              void* d_out, int out_size, void* d_ws, size_t ws_size,
                              hipStream_t stream) {
  const float* x   = (const float*)d_in[0];
  const float* Wq  = (const float*)d_in[1];
  const float* Wk  = (const float*)d_in[2];
  const float* Wv  = (const float*)d_in[3];
  const float* Wo  = (const float*)d_in[4];
  const float* lq1 = (const float*)d_in[5];
  const float* lk1 = (const float*)d_in[6];
  const float* lq2 = (const float*)d_in[7];
  const float* lk2 = (const float*)d_in[8];
  float* out = (float*)d_out;

  char* ws = (char*)d_ws;
  size_t off = 0;
  auto alloc = [&](size_t bytes) -> char* {
    char* p = ws + off;
    off += (bytes + 255) & ~(size_t)255;
    return p;
  };
  bf16_t* xb  = (bf16_t*)alloc((size_t)4096 * 1024 * 2);
  bf16_t* Wqt = (bf16_t*)alloc((size_t)2048 * 1024 * 2);
  bf16_t* Wkt = (bf16_t*)alloc((size_t)2048 * 1024 * 2);
  bf16_t* Wvt = (bf16_t*)alloc((size_t)2048 * 1024 * 2);
  bf16_t* Wot = (bf16_t*)alloc((size_t)1024 * 1024 * 2);
  bf16_t* Qb  = (bf16_t*)alloc((size_t)4096 * 2048 * 2);
  bf16_t* Kb  = (bf16_t*)alloc((size_t)4096 * 2048 * 2);
  bf16_t* Vtg = (bf16_t*)alloc((size_t)4096 * 2048 * 2);
  bf16_t* Ob  = (bf16_t*)alloc((size_t)4096 * 1024 * 2);

  const float QSCALE = 0.125f * 1.44269504088896340736f;  // fold into Wq

  prep_all<<<dim3(64, 32, 5), dim3(32, 8), 0, stream>>>(
      x, xb, Wq, Wk, Wv, Wo, Wqt, Wkt, Wvt, Wot, QSCALE);
  gemm_qkv<<<dim3(16, 32, 3), 256, 0, stream>>>(xb, Wqt, Wkt, Wvt, Qb, Kb, Vtg);
  attn_kernel<<<256, 512, 0, stream>>>(Qb, Kb, Vtg, Ob, lq1, lk1, lq2, lk2);
  gemm_out<<<dim3(8, 32), 256, 0, stream>>>(Ob, Wot, out);
}